// Round 7
// baseline (1639.319 us; speedup 1.0000x reference)
//
#include <hip/hip_runtime.h>
#include <stdint.h>

typedef unsigned short u16;
typedef __bf16 bf16x8 __attribute__((ext_vector_type(8)));
typedef float f32x4 __attribute__((ext_vector_type(4)));

#define N_NODES 50000
#define N_EDGES 800000
#define NTILES  (N_EDGES / 64)
#define LN_EPS 1e-5f

// pack 8 consecutive f32 -> uint4 of 8 bf16 (RNE via hw cvt)
__device__ __forceinline__ uint4 pack8(const float* __restrict__ p) {
    const float4 f0 = ((const float4*)p)[0];
    const float4 f1 = ((const float4*)p)[1];
    union { __bf16 b[8]; uint4 q; } t;
    t.b[0] = (__bf16)f0.x; t.b[1] = (__bf16)f0.y; t.b[2] = (__bf16)f0.z; t.b[3] = (__bf16)f0.w;
    t.b[4] = (__bf16)f1.x; t.b[5] = (__bf16)f1.y; t.b[6] = (__bf16)f1.z; t.b[7] = (__bf16)f1.w;
    return t.q;
}

// ---------------- weight pre-pack ----------------
__global__ void pack_weights(const float* __restrict__ w1e, const float* __restrict__ w2e,
                             const float* __restrict__ w1n, const float* __restrict__ w2n,
                             uint4* __restrict__ out)
{
    const int t = blockIdx.x * 256 + threadIdx.x;
    const float* W; int idx;
    if (t < 6144)       { W = w1e; idx = t; }
    else if (t < 8192)  { W = w2e; idx = t - 6144; }
    else if (t < 12288) { W = w1n; idx = t - 8192; }
    else                { W = w2n; idx = t - 12288; }
    const int lane = idx & 63;
    const int col16 = (idx >> 6) & 7;
    const int kb = idx >> 9;
    const int row0 = kb * 32 + (lane >> 4) * 8;
    const int col = col16 * 16 + (lane & 15);
    union { __bf16 b[8]; uint4 q; } v;
#pragma unroll
    for (int j = 0; j < 8; ++j) v.b[j] = (__bf16)W[(size_t)(row0 + j) * 128 + col];
    out[t] = v.q;
}

// ---------------- f32 -> bf16 streaming converters ----------------
__global__ void convert_node(const float* __restrict__ node, uint4* __restrict__ node_bf) {
    const int idx = blockIdx.x * 256 + threadIdx.x;          // 800,000 chunks
    node_bf[idx] = pack8(node + (size_t)idx * 8);
}
__global__ void convert_elat(const float* __restrict__ elat, uint4* __restrict__ elat_bf) {
    const int idx = blockIdx.x * 256 + threadIdx.x;          // 12.8M chunks
    elat_bf[idx] = pack8(elat + (size_t)idx * 8);
}

// ---------------- Pipelined fused edge kernel ----------------
// x tile: [part0=snd][part1=rcv][part2=elat], 64 rows x 128 bf16, 16B chunks
// XOR-swizzled within row: stored_chunk = chunk ^ (row&7). h1 overlays part0.
// Cross-tile pipeline: data for tile t+stride loaded into registers during
// tile t's compute; indices one tile further ahead.
template<int EBF>
__global__ __launch_bounds__(256, 3)
void edge_pipe(const u16* __restrict__ node_bf,
               const float* __restrict__ elat32, const u16* __restrict__ elat_bf,
               const int* __restrict__ senders, const int* __restrict__ receivers,
               const float* __restrict__ b1, const float* __restrict__ b2,
               const float* __restrict__ gam, const float* __restrict__ bet,
               const uint4* __restrict__ w1p, const uint4* __restrict__ w2p,
               float* __restrict__ eout, float* __restrict__ aggr)
{
    __shared__ __align__(16) u16 x_lds[3 * 64 * 128];   // 48 KB
    __shared__ int rcv_s[64];
    __shared__ float2 part[256];
    __shared__ float muv[64], rsv[64];

    const int tid = threadIdx.x;
    const int w = tid >> 6;
    const int lane = tid & 63;
    const int cl = lane & 15;
    const int q = lane >> 4;
    const int n_base = w * 32;
    const int ch = tid & 15;      // gather chunk lane
    const int r0 = tid >> 4;      // gather row-within-group

    float b1v[2], b2v[2], gv[2], bv[2];
#pragma unroll
    for (int n = 0; n < 2; ++n) {
        const int c = n_base + n * 16 + cl;
        b1v[n] = b1[c]; b2v[n] = b2[c];
        gv[n]  = gam[c]; bv[n] = bet[c];
    }

    const int stride = gridDim.x;

    // ---- pipeline registers ----
    int sn_nxt[4], rc_nxt[4], rc_cur[4];
    uint4 pf_s[4], pf_r[4], pf_e[4];

    // ---- prologue: data(tile0) + idx(tile0+stride) ----
    {
        const int tb = blockIdx.x * 64;
#pragma unroll
        for (int gp = 0; gp < 4; ++gp) {
            sn_nxt[gp] = senders[tb + gp * 16 + r0];
            rc_nxt[gp] = receivers[tb + gp * 16 + r0];
        }
#pragma unroll
        for (int gp = 0; gp < 4; ++gp) {
            pf_s[gp] = ((const uint4*)(node_bf + (size_t)sn_nxt[gp] * 128))[ch];
            pf_r[gp] = ((const uint4*)(node_bf + (size_t)rc_nxt[gp] * 128))[ch];
            if (EBF)
                pf_e[gp] = ((const uint4*)(elat_bf + (size_t)(tb + gp * 16 + r0) * 128))[ch];
            rc_cur[gp] = rc_nxt[gp];
        }
        int t1 = blockIdx.x + stride; if (t1 >= NTILES) t1 = blockIdx.x;
        const int tb1 = t1 * 64;
#pragma unroll
        for (int gp = 0; gp < 4; ++gp) {
            sn_nxt[gp] = senders[tb1 + gp * 16 + r0];
            rc_nxt[gp] = receivers[tb1 + gp * 16 + r0];
        }
    }

    for (int tile = blockIdx.x; tile < NTILES; tile += stride) {
        const int base = tile * 64;

        // ---- 1. commit prefetched tile to LDS ----
#pragma unroll
        for (int gp = 0; gp < 4; ++gp) {
            const int row = gp * 16 + r0;
            const int rx = row & 7;
            uint4* dst = (uint4*)x_lds + row * 16;
            dst[ch ^ rx]          = pf_s[gp];
            dst[1024 + (ch ^ rx)] = pf_r[gp];
            if (EBF) dst[2048 + (ch ^ rx)] = pf_e[gp];
            else     dst[2048 + (ch ^ rx)] = pack8(elat32 + (size_t)(base + gp * 16 + r0) * 128 + ch * 8);
            if (ch == 0) rcv_s[row] = rc_cur[gp];
        }
        __syncthreads();  // A: x tile ready

        // ---- 2. issue prefetch for tile+stride (data) and tile+2*stride (idx) ----
        {
            const int tn = tile + stride;
            if (tn < NTILES) {
                const int tb = tn * 64;
#pragma unroll
                for (int gp = 0; gp < 4; ++gp) {
                    pf_s[gp] = ((const uint4*)(node_bf + (size_t)sn_nxt[gp] * 128))[ch];
                    pf_r[gp] = ((const uint4*)(node_bf + (size_t)rc_nxt[gp] * 128))[ch];
                    if (EBF)
                        pf_e[gp] = ((const uint4*)(elat_bf + (size_t)(tb + gp * 16 + r0) * 128))[ch];
                    rc_cur[gp] = rc_nxt[gp];
                }
                int tnn = tn + stride; if (tnn >= NTILES) tnn = tn;
                const int tb2 = tnn * 64;
#pragma unroll
                for (int gp = 0; gp < 4; ++gp) {
                    sn_nxt[gp] = senders[tb2 + gp * 16 + r0];
                    rc_nxt[gp] = receivers[tb2 + gp * 16 + r0];
                }
            }
        }

        // ---- 3. layer 1: [64,384] x [384,128], weights streamed from L2 ----
        f32x4 acc[4][2];
#pragma unroll
        for (int m = 0; m < 4; ++m)
#pragma unroll
            for (int n = 0; n < 2; ++n)
#pragma unroll
                for (int r = 0; r < 4; ++r) acc[m][n][r] = 0.f;

        uint4 wreg[14][2];
#pragma unroll
        for (int kb = 0; kb < 2; ++kb)
#pragma unroll
            for (int n = 0; n < 2; ++n)
                wreg[kb][n] = w1p[(kb * 8 + w * 2 + n) * 64 + lane];

#pragma unroll
        for (int kb = 0; kb < 12; ++kb) {
            if (kb + 2 < 12) {
#pragma unroll
                for (int n = 0; n < 2; ++n)
                    wreg[kb + 2][n] = w1p[((kb + 2) * 8 + w * 2 + n) * 64 + lane];
            }
            const int p = kb >> 2, k2 = kb & 3;
            bf16x8 a[4];
#pragma unroll
            for (int m = 0; m < 4; ++m) {
                const int row = m * 16 + cl;
                a[m] = __builtin_bit_cast(bf16x8,
                    ((const uint4*)x_lds)[p * 1024 + row * 16 + ((k2 * 4 + q) ^ (row & 7))]);
            }
#pragma unroll
            for (int m = 0; m < 4; ++m)
#pragma unroll
                for (int n = 0; n < 2; ++n)
                    acc[m][n] = __builtin_amdgcn_mfma_f32_16x16x32_bf16(
                        a[m], __builtin_bit_cast(bf16x8, wreg[kb][n]), acc[m][n], 0, 0, 0);
        }

        uint4 w2reg[4][2];
#pragma unroll
        for (int kb = 0; kb < 4; ++kb)
#pragma unroll
            for (int n = 0; n < 2; ++n)
                w2reg[kb][n] = w2p[(kb * 8 + w * 2 + n) * 64 + lane];

        __syncthreads();  // B: part0 dead, pf loads long arrived

        // relu + bias, h1 -> part0 (swizzled)
        {
            __bf16* hb = (__bf16*)x_lds;
#pragma unroll
            for (int m = 0; m < 4; ++m)
#pragma unroll
                for (int n = 0; n < 2; ++n)
#pragma unroll
                    for (int r = 0; r < 4; ++r) {
                        const int row = m * 16 + q * 4 + r;
                        const int col = n_base + n * 16 + cl;
                        hb[row * 128 + (((col >> 3) ^ (row & 7)) << 3) + (col & 7)] =
                            (__bf16)fmaxf(acc[m][n][r] + b1v[n], 0.f);
                    }
        }
        __syncthreads();  // C: h ready

        // ---- 4. layer 2: [64,128] x [128,128] ----
#pragma unroll
        for (int m = 0; m < 4; ++m)
#pragma unroll
            for (int n = 0; n < 2; ++n)
#pragma unroll
                for (int r = 0; r < 4; ++r) acc[m][n][r] = 0.f;
#pragma unroll
        for (int kb = 0; kb < 4; ++kb) {
            bf16x8 a[4];
#pragma unroll
            for (int m = 0; m < 4; ++m) {
                const int row = m * 16 + cl;
                a[m] = __builtin_bit_cast(bf16x8,
                    ((const uint4*)x_lds)[row * 16 + ((kb * 4 + q) ^ (row & 7))]);
            }
#pragma unroll
            for (int m = 0; m < 4; ++m)
#pragma unroll
                for (int n = 0; n < 2; ++n)
                    acc[m][n] = __builtin_amdgcn_mfma_f32_16x16x32_bf16(
                        a[m], __builtin_bit_cast(bf16x8, w2reg[kb][n]), acc[m][n], 0, 0, 0);
        }

#pragma unroll
        for (int m = 0; m < 4; ++m)
#pragma unroll
            for (int n = 0; n < 2; ++n)
#pragma unroll
                for (int r = 0; r < 4; ++r)
                    acc[m][n][r] = fmaxf(acc[m][n][r] + b2v[n], 0.f);

        // ---- 5. LN stats ----
#pragma unroll
        for (int m = 0; m < 4; ++m)
#pragma unroll
            for (int r = 0; r < 4; ++r) {
                float s  = acc[m][0][r] + acc[m][1][r];
                float ss = acc[m][0][r] * acc[m][0][r] + acc[m][1][r] * acc[m][1][r];
#pragma unroll
                for (int off = 1; off < 16; off <<= 1) {
                    s  += __shfl_xor(s, off, 64);
                    ss += __shfl_xor(ss, off, 64);
                }
                if (cl == 0) part[w * 64 + m * 16 + q * 4 + r] = make_float2(s, ss);
            }
        __syncthreads();  // D
        if (tid < 64) {
            float s = 0.f, ss = 0.f;
#pragma unroll
            for (int ww = 0; ww < 4; ++ww) { const float2 pp = part[ww * 64 + tid]; s += pp.x; ss += pp.y; }
            const float mu = s * (1.f / 128.f);
            const float var = ss * (1.f / 128.f) - mu * mu;
            muv[tid] = mu;
            rsv[tid] = rsqrtf(var + LN_EPS);
        }
        __syncthreads();  // E

        // ---- 6. LN + eout (+elat residual from part2) + aggr atomics ----
#pragma unroll
        for (int m = 0; m < 4; ++m)
#pragma unroll
            for (int r = 0; r < 4; ++r) {
                const int row = m * 16 + q * 4 + r;
                const float mu = muv[row];
                const float rs = rsv[row];
                const int rc = rcv_s[row];
                float* orow = eout + (size_t)(base + row) * 128;
#pragma unroll
                for (int n = 0; n < 2; ++n) {
                    const int col = n_base + n * 16 + cl;
                    const float ln = (acc[m][n][r] - mu) * rs * gv[n] + bv[n];
                    atomicAdd(&aggr[(size_t)rc * 128 + col], ln);
                    const float e = (float)((__bf16*)x_lds)[16384 + row * 128 + (((col >> 3) ^ (row & 7)) << 3) + (col & 7)];
                    orow[col] = ln + e;
                }
            }
        __syncthreads();  // F: protect x_lds/rcv_s before next commit
    }
}

// ---------------- Node MLP ----------------
__global__ __launch_bounds__(256, 4)
void node_mlp_kernel(const float* __restrict__ node, const float* __restrict__ aggr,
                     const float* __restrict__ b1, const float* __restrict__ b2,
                     const float* __restrict__ gam, const float* __restrict__ bet,
                     const uint4* __restrict__ w1p, const uint4* __restrict__ w2p,
                     float* __restrict__ nout)
{
    __shared__ __align__(16) u16 x_lds[2 * 64 * 128];
    __shared__ float2 part[256];
    __shared__ float muv[64], rsv[64];

    const int tid = threadIdx.x;
    const int w = tid >> 6;
    const int lane = tid & 63;
    const int cl = lane & 15;
    const int q = lane >> 4;
    const int n_base = w * 32;

    float b1v[2], b2v[2], gv[2], bv[2];
#pragma unroll
    for (int n = 0; n < 2; ++n) {
        const int c = n_base + n * 16 + cl;
        b1v[n] = b1[c]; b2v[n] = b2[c];
        gv[n]  = gam[c]; bv[n] = bet[c];
    }

    const int ntiles = (N_NODES + 63) / 64;
    for (int tile = blockIdx.x; tile < ntiles; tile += gridDim.x) {
        const int base = tile * 64;
        {
            const int ch = tid & 15;
            const int r0 = tid >> 4;
#pragma unroll
            for (int gp = 0; gp < 4; ++gp) {
                const int row = gp * 16 + r0;
                const int rx = row & 7;
                int gn = base + row;
                if (gn >= N_NODES) gn = N_NODES - 1;
                uint4* dst = (uint4*)x_lds + row * 16;
                dst[ch ^ rx]          = pack8(node + (size_t)gn * 128 + ch * 8);
                dst[1024 + (ch ^ rx)] = pack8(aggr + (size_t)gn * 128 + ch * 8);
            }
        }
        __syncthreads();

        f32x4 acc[4][2];
#pragma unroll
        for (int m = 0; m < 4; ++m)
#pragma unroll
            for (int n = 0; n < 2; ++n)
#pragma unroll
                for (int r = 0; r < 4; ++r) acc[m][n][r] = 0.f;
        uint4 wreg[10][2];
#pragma unroll
        for (int kb = 0; kb < 2; ++kb)
#pragma unroll
            for (int n = 0; n < 2; ++n)
                wreg[kb][n] = w1p[(kb * 8 + w * 2 + n) * 64 + lane];
#pragma unroll
        for (int kb = 0; kb < 8; ++kb) {
            if (kb + 2 < 8) {
#pragma unroll
                for (int n = 0; n < 2; ++n)
                    wreg[kb + 2][n] = w1p[((kb + 2) * 8 + w * 2 + n) * 64 + lane];
            }
            const int p = kb >> 2, k2 = kb & 3;
            bf16x8 a[4];
#pragma unroll
            for (int m = 0; m < 4; ++m) {
                const int row = m * 16 + cl;
                a[m] = __builtin_bit_cast(bf16x8,
                    ((const uint4*)x_lds)[p * 1024 + row * 16 + ((k2 * 4 + q) ^ (row & 7))]);
            }
#pragma unroll
            for (int m = 0; m < 4; ++m)
#pragma unroll
                for (int n = 0; n < 2; ++n)
                    acc[m][n] = __builtin_amdgcn_mfma_f32_16x16x32_bf16(
                        a[m], __builtin_bit_cast(bf16x8, wreg[kb][n]), acc[m][n], 0, 0, 0);
        }
        uint4 w2reg[4][2];
#pragma unroll
        for (int kb = 0; kb < 4; ++kb)
#pragma unroll
            for (int n = 0; n < 2; ++n)
                w2reg[kb][n] = w2p[(kb * 8 + w * 2 + n) * 64 + lane];
        __syncthreads();
        {
            __bf16* hb = (__bf16*)(x_lds + 8192);
#pragma unroll
            for (int m = 0; m < 4; ++m)
#pragma unroll
                for (int n = 0; n < 2; ++n)
#pragma unroll
                    for (int r = 0; r < 4; ++r) {
                        const int row = m * 16 + q * 4 + r;
                        const int col = n_base + n * 16 + cl;
                        hb[row * 128 + (((col >> 3) ^ (row & 7)) << 3) + (col & 7)] =
                            (__bf16)fmaxf(acc[m][n][r] + b1v[n], 0.f);
                    }
        }
        __syncthreads();
#pragma unroll
        for (int m = 0; m < 4; ++m)
#pragma unroll
            for (int n = 0; n < 2; ++n)
#pragma unroll
                for (int r = 0; r < 4; ++r) acc[m][n][r] = 0.f;
#pragma unroll
        for (int kb = 0; kb < 4; ++kb) {
            bf16x8 a[4];
#pragma unroll
            for (int m = 0; m < 4; ++m) {
                const int row = m * 16 + cl;
                a[m] = __builtin_bit_cast(bf16x8,
                    ((const uint4*)x_lds)[1024 + row * 16 + ((kb * 4 + q) ^ (row & 7))]);
            }
#pragma unroll
            for (int m = 0; m < 4; ++m)
#pragma unroll
                for (int n = 0; n < 2; ++n)
                    acc[m][n] = __builtin_amdgcn_mfma_f32_16x16x32_bf16(
                        a[m], __builtin_bit_cast(bf16x8, w2reg[kb][n]), acc[m][n], 0, 0, 0);
        }
#pragma unroll
        for (int m = 0; m < 4; ++m)
#pragma unroll
            for (int n = 0; n < 2; ++n)
#pragma unroll
                for (int r = 0; r < 4; ++r)
                    acc[m][n][r] = fmaxf(acc[m][n][r] + b2v[n], 0.f);
#pragma unroll
        for (int m = 0; m < 4; ++m)
#pragma unroll
            for (int r = 0; r < 4; ++r) {
                float s  = acc[m][0][r] + acc[m][1][r];
                float ss = acc[m][0][r] * acc[m][0][r] + acc[m][1][r] * acc[m][1][r];
#pragma unroll
                for (int off = 1; off < 16; off <<= 1) {
                    s  += __shfl_xor(s, off, 64);
                    ss += __shfl_xor(ss, off, 64);
                }
                if (cl == 0) part[w * 64 + m * 16 + q * 4 + r] = make_float2(s, ss);
            }
        __syncthreads();
        if (tid < 64) {
            float s = 0.f, ss = 0.f;
#pragma unroll
            for (int ww = 0; ww < 4; ++ww) { const float2 pp = part[ww * 64 + tid]; s += pp.x; ss += pp.y; }
            const float mu = s * (1.f / 128.f);
            const float var = ss * (1.f / 128.f) - mu * mu;
            muv[tid] = mu;
            rsv[tid] = rsqrtf(var + LN_EPS);
        }
        __syncthreads();
#pragma unroll
        for (int m = 0; m < 4; ++m)
#pragma unroll
            for (int r = 0; r < 4; ++r) {
                const int row = m * 16 + q * 4 + r;
                if (base + row < N_NODES) {
                    const float mu = muv[row];
                    const float rs = rsv[row];
                    float* orow = nout + (size_t)(base + row) * 128;
#pragma unroll
                    for (int n = 0; n < 2; ++n) {
                        const int col = n_base + n * 16 + cl;
                        const float ln = (acc[m][n][r] - mu) * rs * gv[n] + bv[n];
                        const float e = (float)((__bf16*)x_lds)[row * 128 + (((col >> 3) ^ (row & 7)) << 3) + (col & 7)];
                        orow[col] = ln + e;
                    }
                }
            }
        __syncthreads();
    }
}

extern "C" void kernel_launch(void* const* d_in, const int* in_sizes, int n_in,
                              void* d_out, int out_size, void* d_ws, size_t ws_size,
                              hipStream_t stream) {
    (void)in_sizes; (void)n_in; (void)out_size;
    const float* node = (const float*)d_in[0];
    const float* elat = (const float*)d_in[1];
    const int* senders = (const int*)d_in[2];
    const int* receivers = (const int*)d_in[3];
    const float* me_w1 = (const float*)d_in[4];
    const float* me_b1 = (const float*)d_in[5];
    const float* me_w2 = (const float*)d_in[6];
    const float* me_b2 = (const float*)d_in[7];
    const float* me_g  = (const float*)d_in[8];
    const float* me_be = (const float*)d_in[9];
    const float* nf_w1 = (const float*)d_in[10];
    const float* nf_b1 = (const float*)d_in[11];
    const float* nf_w2 = (const float*)d_in[12];
    const float* nf_b2 = (const float*)d_in[13];
    const float* nf_g  = (const float*)d_in[14];
    const float* nf_be = (const float*)d_in[15];

    float* out_nodes = (float*)d_out;
    float* out_edges = out_nodes + (size_t)N_NODES * 128;

    // d_out scratch (free until node_mlp, which runs last): bf16 node table
    u16* node_bf = (u16*)d_out;                                      // 12.8 MB

    // ws layout
    char* ws = (char*)d_ws;
    const size_t off_aggr   = 0;
    const size_t off_wpack  = off_aggr  + (size_t)N_NODES * 128 * sizeof(float);  // 25,600,000
    const size_t off_elat   = off_wpack + 14336 * sizeof(uint4);                  // 25,829,376
    const size_t need_min   = off_elat;
    const size_t need_ebf   = off_elat + (size_t)N_EDGES * 128 * sizeof(u16);     // ~230.6 MB
    if (ws_size < need_min) return;

    float* aggr    = (float*)(ws + off_aggr);
    uint4* wpack   = (uint4*)(ws + off_wpack);
    u16*   elat_bf = (u16*)(ws + off_elat);
    const bool ebf = (ws_size >= need_ebf);

    hipMemsetAsync(aggr, 0, (size_t)N_NODES * 128 * sizeof(float), stream);
    pack_weights<<<56, 256, 0, stream>>>(me_w1, me_w2, nf_w1, nf_w2, wpack);
    convert_node<<<3125, 256, 0, stream>>>(node, (uint4*)node_bf);

    if (ebf) {
        convert_elat<<<50000, 256, 0, stream>>>(elat, (uint4*)elat_bf);
        edge_pipe<1><<<768, 256, 0, stream>>>(node_bf, elat, elat_bf, senders, receivers,
                                              me_b1, me_b2, me_g, me_be,
                                              wpack, wpack + 6144,
                                              out_edges, aggr);
    } else {
        edge_pipe<0><<<768, 256, 0, stream>>>(node_bf, elat, elat_bf, senders, receivers,
                                              me_b1, me_b2, me_g, me_be,
                                              wpack, wpack + 6144,
                                              out_edges, aggr);
    }
    node_mlp_kernel<<<782, 256, 0, stream>>>(node, aggr,
                                             nf_b1, nf_b2, nf_g, nf_be,
                                             wpack + 8192, wpack + 12288,
                                             out_nodes);
}

// Round 8
// 1283.860 us; speedup vs baseline: 1.2769x; 1.2769x over previous
//
#include <hip/hip_runtime.h>
#include <stdint.h>

typedef unsigned short u16;
typedef __bf16 bf16x8 __attribute__((ext_vector_type(8)));
typedef float f32x4 __attribute__((ext_vector_type(4)));

#define N_NODES 50000
#define N_EDGES 800000
#define NTILES  (N_EDGES / 64)
#define LN_EPS 1e-5f

// pack 8 consecutive f32 -> uint4 of 8 bf16 (RNE via hw cvt)
__device__ __forceinline__ uint4 pack8(const float* __restrict__ p) {
    const float4 f0 = ((const float4*)p)[0];
    const float4 f1 = ((const float4*)p)[1];
    union { __bf16 b[8]; uint4 q; } t;
    t.b[0] = (__bf16)f0.x; t.b[1] = (__bf16)f0.y; t.b[2] = (__bf16)f0.z; t.b[3] = (__bf16)f0.w;
    t.b[4] = (__bf16)f1.x; t.b[5] = (__bf16)f1.y; t.b[6] = (__bf16)f1.z; t.b[7] = (__bf16)f1.w;
    return t.q;
}

// ---------------- weight pre-pack ----------------
__global__ void pack_weights(const float* __restrict__ w1e, const float* __restrict__ w2e,
                             const float* __restrict__ w1n, const float* __restrict__ w2n,
                             uint4* __restrict__ out)
{
    const int t = blockIdx.x * 256 + threadIdx.x;
    const float* W; int idx;
    if (t < 6144)       { W = w1e; idx = t; }
    else if (t < 8192)  { W = w2e; idx = t - 6144; }
    else if (t < 12288) { W = w1n; idx = t - 8192; }
    else                { W = w2n; idx = t - 12288; }
    const int lane = idx & 63;
    const int col16 = (idx >> 6) & 7;
    const int kb = idx >> 9;
    const int row0 = kb * 32 + (lane >> 4) * 8;
    const int col = col16 * 16 + (lane & 15);
    union { __bf16 b[8]; uint4 q; } v;
#pragma unroll
    for (int j = 0; j < 8; ++j) v.b[j] = (__bf16)W[(size_t)(row0 + j) * 128 + col];
    out[t] = v.q;
}

// ---------------- f32 -> bf16 streaming converters ----------------
__global__ void convert_node(const float* __restrict__ node, uint4* __restrict__ node_bf) {
    const int idx = blockIdx.x * 256 + threadIdx.x;          // 800,000 chunks
    node_bf[idx] = pack8(node + (size_t)idx * 8);
}
__global__ void convert_elat(const float* __restrict__ elat, uint4* __restrict__ elat_bf) {
    const int idx = blockIdx.x * 256 + threadIdx.x;          // 12.8M chunks
    elat_bf[idx] = pack8(elat + (size_t)idx * 8);
}

// ---------------- Pipelined fused edge kernel ----------------
// Identical to r7 except __launch_bounds__(256,2): register budget 256/thread
// so the 12-uint4 cross-tile prefetch stays in VGPRs (r7 spilled at budget 170).
// x tile: [part0=snd][part1=rcv][part2=elat], 64 rows x 128 bf16, 16B chunks
// XOR-swizzled within row: stored_chunk = chunk ^ (row&7). h1 overlays part0.
template<int EBF>
__global__ __launch_bounds__(256, 2)
void edge_pipe(const u16* __restrict__ node_bf,
               const float* __restrict__ elat32, const u16* __restrict__ elat_bf,
               const int* __restrict__ senders, const int* __restrict__ receivers,
               const float* __restrict__ b1, const float* __restrict__ b2,
               const float* __restrict__ gam, const float* __restrict__ bet,
               const uint4* __restrict__ w1p, const uint4* __restrict__ w2p,
               float* __restrict__ eout, float* __restrict__ aggr)
{
    __shared__ __align__(16) u16 x_lds[3 * 64 * 128];   // 48 KB
    __shared__ int rcv_s[64];
    __shared__ float2 part[256];
    __shared__ float muv[64], rsv[64];

    const int tid = threadIdx.x;
    const int w = tid >> 6;
    const int lane = tid & 63;
    const int cl = lane & 15;
    const int q = lane >> 4;
    const int n_base = w * 32;
    const int ch = tid & 15;      // gather chunk lane
    const int r0 = tid >> 4;      // gather row-within-group

    float b1v[2], b2v[2], gv[2], bv[2];
#pragma unroll
    for (int n = 0; n < 2; ++n) {
        const int c = n_base + n * 16 + cl;
        b1v[n] = b1[c]; b2v[n] = b2[c];
        gv[n]  = gam[c]; bv[n] = bet[c];
    }

    const int stride = gridDim.x;

    // ---- pipeline registers ----
    int sn_nxt[4], rc_nxt[4], rc_cur[4];
    uint4 pf_s[4], pf_r[4], pf_e[4];

    // ---- prologue: data(tile0) + idx(tile0+stride) ----
    {
        const int tb = blockIdx.x * 64;
#pragma unroll
        for (int gp = 0; gp < 4; ++gp) {
            sn_nxt[gp] = senders[tb + gp * 16 + r0];
            rc_nxt[gp] = receivers[tb + gp * 16 + r0];
        }
#pragma unroll
        for (int gp = 0; gp < 4; ++gp) {
            pf_s[gp] = ((const uint4*)(node_bf + (size_t)sn_nxt[gp] * 128))[ch];
            pf_r[gp] = ((const uint4*)(node_bf + (size_t)rc_nxt[gp] * 128))[ch];
            if (EBF)
                pf_e[gp] = ((const uint4*)(elat_bf + (size_t)(tb + gp * 16 + r0) * 128))[ch];
            rc_cur[gp] = rc_nxt[gp];
        }
        int t1 = blockIdx.x + stride; if (t1 >= NTILES) t1 = blockIdx.x;
        const int tb1 = t1 * 64;
#pragma unroll
        for (int gp = 0; gp < 4; ++gp) {
            sn_nxt[gp] = senders[tb1 + gp * 16 + r0];
            rc_nxt[gp] = receivers[tb1 + gp * 16 + r0];
        }
    }

    for (int tile = blockIdx.x; tile < NTILES; tile += stride) {
        const int base = tile * 64;

        // ---- 1. commit prefetched tile to LDS ----
#pragma unroll
        for (int gp = 0; gp < 4; ++gp) {
            const int row = gp * 16 + r0;
            const int rx = row & 7;
            uint4* dst = (uint4*)x_lds + row * 16;
            dst[ch ^ rx]          = pf_s[gp];
            dst[1024 + (ch ^ rx)] = pf_r[gp];
            if (EBF) dst[2048 + (ch ^ rx)] = pf_e[gp];
            else     dst[2048 + (ch ^ rx)] = pack8(elat32 + (size_t)(base + gp * 16 + r0) * 128 + ch * 8);
            if (ch == 0) rcv_s[row] = rc_cur[gp];
        }
        __syncthreads();  // A: x tile ready

        // ---- 2. issue prefetch for tile+stride (data) and tile+2*stride (idx) ----
        {
            const int tn = tile + stride;
            if (tn < NTILES) {
                const int tb = tn * 64;
#pragma unroll
                for (int gp = 0; gp < 4; ++gp) {
                    pf_s[gp] = ((const uint4*)(node_bf + (size_t)sn_nxt[gp] * 128))[ch];
                    pf_r[gp] = ((const uint4*)(node_bf + (size_t)rc_nxt[gp] * 128))[ch];
                    if (EBF)
                        pf_e[gp] = ((const uint4*)(elat_bf + (size_t)(tb + gp * 16 + r0) * 128))[ch];
                    rc_cur[gp] = rc_nxt[gp];
                }
                int tnn = tn + stride; if (tnn >= NTILES) tnn = tn;
                const int tb2 = tnn * 64;
#pragma unroll
                for (int gp = 0; gp < 4; ++gp) {
                    sn_nxt[gp] = senders[tb2 + gp * 16 + r0];
                    rc_nxt[gp] = receivers[tb2 + gp * 16 + r0];
                }
            }
        }

        // ---- 3. layer 1: [64,384] x [384,128], weights streamed from L2 ----
        f32x4 acc[4][2];
#pragma unroll
        for (int m = 0; m < 4; ++m)
#pragma unroll
            for (int n = 0; n < 2; ++n)
#pragma unroll
                for (int r = 0; r < 4; ++r) acc[m][n][r] = 0.f;

        uint4 wreg[14][2];
#pragma unroll
        for (int kb = 0; kb < 2; ++kb)
#pragma unroll
            for (int n = 0; n < 2; ++n)
                wreg[kb][n] = w1p[(kb * 8 + w * 2 + n) * 64 + lane];

#pragma unroll
        for (int kb = 0; kb < 12; ++kb) {
            if (kb + 2 < 12) {
#pragma unroll
                for (int n = 0; n < 2; ++n)
                    wreg[kb + 2][n] = w1p[((kb + 2) * 8 + w * 2 + n) * 64 + lane];
            }
            const int p = kb >> 2, k2 = kb & 3;
            bf16x8 a[4];
#pragma unroll
            for (int m = 0; m < 4; ++m) {
                const int row = m * 16 + cl;
                a[m] = __builtin_bit_cast(bf16x8,
                    ((const uint4*)x_lds)[p * 1024 + row * 16 + ((k2 * 4 + q) ^ (row & 7))]);
            }
#pragma unroll
            for (int m = 0; m < 4; ++m)
#pragma unroll
                for (int n = 0; n < 2; ++n)
                    acc[m][n] = __builtin_amdgcn_mfma_f32_16x16x32_bf16(
                        a[m], __builtin_bit_cast(bf16x8, wreg[kb][n]), acc[m][n], 0, 0, 0);
        }

        uint4 w2reg[4][2];
#pragma unroll
        for (int kb = 0; kb < 4; ++kb)
#pragma unroll
            for (int n = 0; n < 2; ++n)
                w2reg[kb][n] = w2p[(kb * 8 + w * 2 + n) * 64 + lane];

        __syncthreads();  // B: part0 dead, pf loads long arrived

        // relu + bias, h1 -> part0 (swizzled)
        {
            __bf16* hb = (__bf16*)x_lds;
#pragma unroll
            for (int m = 0; m < 4; ++m)
#pragma unroll
                for (int n = 0; n < 2; ++n)
#pragma unroll
                    for (int r = 0; r < 4; ++r) {
                        const int row = m * 16 + q * 4 + r;
                        const int col = n_base + n * 16 + cl;
                        hb[row * 128 + (((col >> 3) ^ (row & 7)) << 3) + (col & 7)] =
                            (__bf16)fmaxf(acc[m][n][r] + b1v[n], 0.f);
                    }
        }
        __syncthreads();  // C: h ready

        // ---- 4. layer 2: [64,128] x [128,128] ----
#pragma unroll
        for (int m = 0; m < 4; ++m)
#pragma unroll
            for (int n = 0; n < 2; ++n)
#pragma unroll
                for (int r = 0; r < 4; ++r) acc[m][n][r] = 0.f;
#pragma unroll
        for (int kb = 0; kb < 4; ++kb) {
            bf16x8 a[4];
#pragma unroll
            for (int m = 0; m < 4; ++m) {
                const int row = m * 16 + cl;
                a[m] = __builtin_bit_cast(bf16x8,
                    ((const uint4*)x_lds)[row * 16 + ((kb * 4 + q) ^ (row & 7))]);
            }
#pragma unroll
            for (int m = 0; m < 4; ++m)
#pragma unroll
                for (int n = 0; n < 2; ++n)
                    acc[m][n] = __builtin_amdgcn_mfma_f32_16x16x32_bf16(
                        a[m], __builtin_bit_cast(bf16x8, w2reg[kb][n]), acc[m][n], 0, 0, 0);
        }

#pragma unroll
        for (int m = 0; m < 4; ++m)
#pragma unroll
            for (int n = 0; n < 2; ++n)
#pragma unroll
                for (int r = 0; r < 4; ++r)
                    acc[m][n][r] = fmaxf(acc[m][n][r] + b2v[n], 0.f);

        // ---- 5. LN stats ----
#pragma unroll
        for (int m = 0; m < 4; ++m)
#pragma unroll
            for (int r = 0; r < 4; ++r) {
                float s  = acc[m][0][r] + acc[m][1][r];
                float ss = acc[m][0][r] * acc[m][0][r] + acc[m][1][r] * acc[m][1][r];
#pragma unroll
                for (int off = 1; off < 16; off <<= 1) {
                    s  += __shfl_xor(s, off, 64);
                    ss += __shfl_xor(ss, off, 64);
                }
                if (cl == 0) part[w * 64 + m * 16 + q * 4 + r] = make_float2(s, ss);
            }
        __syncthreads();  // D
        if (tid < 64) {
            float s = 0.f, ss = 0.f;
#pragma unroll
            for (int ww = 0; ww < 4; ++ww) { const float2 pp = part[ww * 64 + tid]; s += pp.x; ss += pp.y; }
            const float mu = s * (1.f / 128.f);
            const float var = ss * (1.f / 128.f) - mu * mu;
            muv[tid] = mu;
            rsv[tid] = rsqrtf(var + LN_EPS);
        }
        __syncthreads();  // E

        // ---- 6. LN + eout (+elat residual from part2) + aggr atomics ----
#pragma unroll
        for (int m = 0; m < 4; ++m)
#pragma unroll
            for (int r = 0; r < 4; ++r) {
                const int row = m * 16 + q * 4 + r;
                const float mu = muv[row];
                const float rs = rsv[row];
                const int rc = rcv_s[row];
                float* orow = eout + (size_t)(base + row) * 128;
#pragma unroll
                for (int n = 0; n < 2; ++n) {
                    const int col = n_base + n * 16 + cl;
                    const float ln = (acc[m][n][r] - mu) * rs * gv[n] + bv[n];
                    atomicAdd(&aggr[(size_t)rc * 128 + col], ln);
                    const float e = (float)((__bf16*)x_lds)[16384 + row * 128 + (((col >> 3) ^ (row & 7)) << 3) + (col & 7)];
                    orow[col] = ln + e;
                }
            }
        __syncthreads();  // F: protect x_lds/rcv_s before next commit
    }
}

// ---------------- Node MLP ----------------
__global__ __launch_bounds__(256, 4)
void node_mlp_kernel(const float* __restrict__ node, const float* __restrict__ aggr,
                     const float* __restrict__ b1, const float* __restrict__ b2,
                     const float* __restrict__ gam, const float* __restrict__ bet,
                     const uint4* __restrict__ w1p, const uint4* __restrict__ w2p,
                     float* __restrict__ nout)
{
    __shared__ __align__(16) u16 x_lds[2 * 64 * 128];
    __shared__ float2 part[256];
    __shared__ float muv[64], rsv[64];

    const int tid = threadIdx.x;
    const int w = tid >> 6;
    const int lane = tid & 63;
    const int cl = lane & 15;
    const int q = lane >> 4;
    const int n_base = w * 32;

    float b1v[2], b2v[2], gv[2], bv[2];
#pragma unroll
    for (int n = 0; n < 2; ++n) {
        const int c = n_base + n * 16 + cl;
        b1v[n] = b1[c]; b2v[n] = b2[c];
        gv[n]  = gam[c]; bv[n] = bet[c];
    }

    const int ntiles = (N_NODES + 63) / 64;
    for (int tile = blockIdx.x; tile < ntiles; tile += gridDim.x) {
        const int base = tile * 64;
        {
            const int ch = tid & 15;
            const int r0 = tid >> 4;
#pragma unroll
            for (int gp = 0; gp < 4; ++gp) {
                const int row = gp * 16 + r0;
                const int rx = row & 7;
                int gn = base + row;
                if (gn >= N_NODES) gn = N_NODES - 1;
                uint4* dst = (uint4*)x_lds + row * 16;
                dst[ch ^ rx]          = pack8(node + (size_t)gn * 128 + ch * 8);
                dst[1024 + (ch ^ rx)] = pack8(aggr + (size_t)gn * 128 + ch * 8);
            }
        }
        __syncthreads();

        f32x4 acc[4][2];
#pragma unroll
        for (int m = 0; m < 4; ++m)
#pragma unroll
            for (int n = 0; n < 2; ++n)
#pragma unroll
                for (int r = 0; r < 4; ++r) acc[m][n][r] = 0.f;
        uint4 wreg[10][2];
#pragma unroll
        for (int kb = 0; kb < 2; ++kb)
#pragma unroll
            for (int n = 0; n < 2; ++n)
                wreg[kb][n] = w1p[(kb * 8 + w * 2 + n) * 64 + lane];
#pragma unroll
        for (int kb = 0; kb < 8; ++kb) {
            if (kb + 2 < 8) {
#pragma unroll
                for (int n = 0; n < 2; ++n)
                    wreg[kb + 2][n] = w1p[((kb + 2) * 8 + w * 2 + n) * 64 + lane];
            }
            const int p = kb >> 2, k2 = kb & 3;
            bf16x8 a[4];
#pragma unroll
            for (int m = 0; m < 4; ++m) {
                const int row = m * 16 + cl;
                a[m] = __builtin_bit_cast(bf16x8,
                    ((const uint4*)x_lds)[p * 1024 + row * 16 + ((k2 * 4 + q) ^ (row & 7))]);
            }
#pragma unroll
            for (int m = 0; m < 4; ++m)
#pragma unroll
                for (int n = 0; n < 2; ++n)
                    acc[m][n] = __builtin_amdgcn_mfma_f32_16x16x32_bf16(
                        a[m], __builtin_bit_cast(bf16x8, wreg[kb][n]), acc[m][n], 0, 0, 0);
        }
        uint4 w2reg[4][2];
#pragma unroll
        for (int kb = 0; kb < 4; ++kb)
#pragma unroll
            for (int n = 0; n < 2; ++n)
                w2reg[kb][n] = w2p[(kb * 8 + w * 2 + n) * 64 + lane];
        __syncthreads();
        {
            __bf16* hb = (__bf16*)(x_lds + 8192);
#pragma unroll
            for (int m = 0; m < 4; ++m)
#pragma unroll
                for (int n = 0; n < 2; ++n)
#pragma unroll
                    for (int r = 0; r < 4; ++r) {
                        const int row = m * 16 + q * 4 + r;
                        const int col = n_base + n * 16 + cl;
                        hb[row * 128 + (((col >> 3) ^ (row & 7)) << 3) + (col & 7)] =
                            (__bf16)fmaxf(acc[m][n][r] + b1v[n], 0.f);
                    }
        }
        __syncthreads();
#pragma unroll
        for (int m = 0; m < 4; ++m)
#pragma unroll
            for (int n = 0; n < 2; ++n)
#pragma unroll
                for (int r = 0; r < 4; ++r) acc[m][n][r] = 0.f;
#pragma unroll
        for (int kb = 0; kb < 4; ++kb) {
            bf16x8 a[4];
#pragma unroll
            for (int m = 0; m < 4; ++m) {
                const int row = m * 16 + cl;
                a[m] = __builtin_bit_cast(bf16x8,
                    ((const uint4*)x_lds)[1024 + row * 16 + ((kb * 4 + q) ^ (row & 7))]);
            }
#pragma unroll
            for (int m = 0; m < 4; ++m)
#pragma unroll
                for (int n = 0; n < 2; ++n)
                    acc[m][n] = __builtin_amdgcn_mfma_f32_16x16x32_bf16(
                        a[m], __builtin_bit_cast(bf16x8, w2reg[kb][n]), acc[m][n], 0, 0, 0);
        }
#pragma unroll
        for (int m = 0; m < 4; ++m)
#pragma unroll
            for (int n = 0; n < 2; ++n)
#pragma unroll
                for (int r = 0; r < 4; ++r)
                    acc[m][n][r] = fmaxf(acc[m][n][r] + b2v[n], 0.f);
#pragma unroll
        for (int m = 0; m < 4; ++m)
#pragma unroll
            for (int r = 0; r < 4; ++r) {
                float s  = acc[m][0][r] + acc[m][1][r];
                float ss = acc[m][0][r] * acc[m][0][r] + acc[m][1][r] * acc[m][1][r];
#pragma unroll
                for (int off = 1; off < 16; off <<= 1) {
                    s  += __shfl_xor(s, off, 64);
                    ss += __shfl_xor(ss, off, 64);
                }
                if (cl == 0) part[w * 64 + m * 16 + q * 4 + r] = make_float2(s, ss);
            }
        __syncthreads();
        if (tid < 64) {
            float s = 0.f, ss = 0.f;
#pragma unroll
            for (int ww = 0; ww < 4; ++ww) { const float2 pp = part[ww * 64 + tid]; s += pp.x; ss += pp.y; }
            const float mu = s * (1.f / 128.f);
            const float var = ss * (1.f / 128.f) - mu * mu;
            muv[tid] = mu;
            rsv[tid] = rsqrtf(var + LN_EPS);
        }
        __syncthreads();
#pragma unroll
        for (int m = 0; m < 4; ++m)
#pragma unroll
            for (int r = 0; r < 4; ++r) {
                const int row = m * 16 + q * 4 + r;
                if (base + row < N_NODES) {
                    const float mu = muv[row];
                    const float rs = rsv[row];
                    float* orow = nout + (size_t)(base + row) * 128;
#pragma unroll
                    for (int n = 0; n < 2; ++n) {
                        const int col = n_base + n * 16 + cl;
                        const float ln = (acc[m][n][r] - mu) * rs * gv[n] + bv[n];
                        const float e = (float)((__bf16*)x_lds)[row * 128 + (((col >> 3) ^ (row & 7)) << 3) + (col & 7)];
                        orow[col] = ln + e;
                    }
                }
            }
        __syncthreads();
    }
}

extern "C" void kernel_launch(void* const* d_in, const int* in_sizes, int n_in,
                              void* d_out, int out_size, void* d_ws, size_t ws_size,
                              hipStream_t stream) {
    (void)in_sizes; (void)n_in; (void)out_size;
    const float* node = (const float*)d_in[0];
    const float* elat = (const float*)d_in[1];
    const int* senders = (const int*)d_in[2];
    const int* receivers = (const int*)d_in[3];
    const float* me_w1 = (const float*)d_in[4];
    const float* me_b1 = (const float*)d_in[5];
    const float* me_w2 = (const float*)d_in[6];
    const float* me_b2 = (const float*)d_in[7];
    const float* me_g  = (const float*)d_in[8];
    const float* me_be = (const float*)d_in[9];
    const float* nf_w1 = (const float*)d_in[10];
    const float* nf_b1 = (const float*)d_in[11];
    const float* nf_w2 = (const float*)d_in[12];
    const float* nf_b2 = (const float*)d_in[13];
    const float* nf_g  = (const float*)d_in[14];
    const float* nf_be = (const float*)d_in[15];

    float* out_nodes = (float*)d_out;
    float* out_edges = out_nodes + (size_t)N_NODES * 128;

    // d_out scratch (free until node_mlp, which runs last): bf16 node table
    u16* node_bf = (u16*)d_out;                                      // 12.8 MB

    // ws layout
    char* ws = (char*)d_ws;
    const size_t off_aggr   = 0;
    const size_t off_wpack  = off_aggr  + (size_t)N_NODES * 128 * sizeof(float);  // 25,600,000
    const size_t off_elat   = off_wpack + 14336 * sizeof(uint4);                  // 25,829,376
    const size_t need_min   = off_elat;
    const size_t need_ebf   = off_elat + (size_t)N_EDGES * 128 * sizeof(u16);     // ~230.6 MB
    if (ws_size < need_min) return;

    float* aggr    = (float*)(ws + off_aggr);
    uint4* wpack   = (uint4*)(ws + off_wpack);
    u16*   elat_bf = (u16*)(ws + off_elat);
    const bool ebf = (ws_size >= need_ebf);

    hipMemsetAsync(aggr, 0, (size_t)N_NODES * 128 * sizeof(float), stream);
    pack_weights<<<56, 256, 0, stream>>>(me_w1, me_w2, nf_w1, nf_w2, wpack);
    convert_node<<<3125, 256, 0, stream>>>(node, (uint4*)node_bf);

    if (ebf) {
        convert_elat<<<50000, 256, 0, stream>>>(elat, (uint4*)elat_bf);
        edge_pipe<1><<<512, 256, 0, stream>>>(node_bf, elat, elat_bf, senders, receivers,
                                              me_b1, me_b2, me_g, me_be,
                                              wpack, wpack + 6144,
                                              out_edges, aggr);
    } else {
        edge_pipe<0><<<512, 256, 0, stream>>>(node_bf, elat, elat_bf, senders, receivers,
                                              me_b1, me_b2, me_g, me_be,
                                              wpack, wpack + 6144,
                                              out_edges, aggr);
    }
    node_mlp_kernel<<<782, 256, 0, stream>>>(node, aggr,
                                             nf_b1, nf_b2, nf_g, nf_be,
                                             wpack + 8192, wpack + 12288,
                                             out_nodes);
}

// Round 9
// 1269.660 us; speedup vs baseline: 1.2911x; 1.0112x over previous
//
#include <hip/hip_runtime.h>
#include <stdint.h>

typedef unsigned short u16;
typedef __bf16 bf16x8 __attribute__((ext_vector_type(8)));
typedef float f32x4 __attribute__((ext_vector_type(4)));

#define N_NODES 50000
#define N_EDGES 800000
#define TROWS   32
#define NT      (N_EDGES / TROWS)    // 25000
#define LN_EPS  1e-5f

// async 16B global -> LDS (zero VGPR staging). LDS dest is wave-uniform base;
// HW writes at base + lane*16. Global src is per-lane.
__device__ __forceinline__ void async16(const void* g, void* l) {
    __builtin_amdgcn_global_load_lds(
        (const __attribute__((address_space(1))) unsigned int*)g,
        (__attribute__((address_space(3))) unsigned int*)l, 16, 0, 0);
}

// pack 8 consecutive f32 -> uint4 of 8 bf16 (RNE via hw cvt)
__device__ __forceinline__ uint4 pack8(const float* __restrict__ p) {
    const float4 f0 = ((const float4*)p)[0];
    const float4 f1 = ((const float4*)p)[1];
    union { __bf16 b[8]; uint4 q; } t;
    t.b[0] = (__bf16)f0.x; t.b[1] = (__bf16)f0.y; t.b[2] = (__bf16)f0.z; t.b[3] = (__bf16)f0.w;
    t.b[4] = (__bf16)f1.x; t.b[5] = (__bf16)f1.y; t.b[6] = (__bf16)f1.z; t.b[7] = (__bf16)f1.w;
    return t.q;
}

// ---------------- weight pre-pack ----------------
__global__ void pack_weights(const float* __restrict__ w1e, const float* __restrict__ w2e,
                             const float* __restrict__ w1n, const float* __restrict__ w2n,
                             uint4* __restrict__ out)
{
    const int t = blockIdx.x * 256 + threadIdx.x;
    const float* W; int idx;
    if (t < 6144)       { W = w1e; idx = t; }
    else if (t < 8192)  { W = w2e; idx = t - 6144; }
    else if (t < 12288) { W = w1n; idx = t - 8192; }
    else                { W = w2n; idx = t - 12288; }
    const int lane = idx & 63;
    const int col16 = (idx >> 6) & 7;
    const int kb = idx >> 9;
    const int row0 = kb * 32 + (lane >> 4) * 8;
    const int col = col16 * 16 + (lane & 15);
    union { __bf16 b[8]; uint4 q; } v;
#pragma unroll
    for (int j = 0; j < 8; ++j) v.b[j] = (__bf16)W[(size_t)(row0 + j) * 128 + col];
    out[t] = v.q;
}

// ---------------- f32 -> bf16 streaming converters ----------------
__global__ void convert_node(const float* __restrict__ node, uint4* __restrict__ node_bf) {
    const int idx = blockIdx.x * 256 + threadIdx.x;          // 800,000 chunks
    node_bf[idx] = pack8(node + (size_t)idx * 8);
}
__global__ void convert_elat(const float* __restrict__ elat, uint4* __restrict__ elat_bf) {
    const int idx = blockIdx.x * 256 + threadIdx.x;          // 12.8M chunks
    elat_bf[idx] = pack8(elat + (size_t)idx * 8);
}

// ---------------- Async double-buffered fused edge kernel ----------------
// 32-edge tiles. x buffer: [part0=snd][part1=rcv][part2=elat], 32 rows x 128 bf16
// per part, 16B chunks XOR-swizzled (stored_chunk = chunk ^ (row&7)) -- swizzle
// applied on the SOURCE address; LDS dest is linear (global_load_lds constraint).
// Double-buffered: tile t+stride staged asynchronously during tile t's compute;
// the staging loads drain at each wave's first barrier (after L1) instead of
// being consumed immediately -- HBM latency/service overlaps MFMA.
// h1 overlays part0 of cur after L1.
template<int EBF>
__global__ __launch_bounds__(256, 3)
void edge_async(const u16* __restrict__ node_bf,
                const float* __restrict__ elat32, const u16* __restrict__ elat_bf,
                const int* __restrict__ senders, const int* __restrict__ receivers,
                const float* __restrict__ b1, const float* __restrict__ b2,
                const float* __restrict__ gam, const float* __restrict__ bet,
                const uint4* __restrict__ w1p, const uint4* __restrict__ w2p,
                float* __restrict__ eout, float* __restrict__ aggr)
{
    __shared__ __align__(16) u16 xb[2][3 * TROWS * 128];   // 2 x 24 KB
    __shared__ int rcv_b[2][TROWS];
    __shared__ float2 part[128];
    __shared__ float muv[TROWS], rsv[TROWS];

    const int tid = threadIdx.x;
    const int w = tid >> 6;
    const int lane = tid & 63;
    const int cl = lane & 15;
    const int q = lane >> 4;
    const int n_base = w * 32;

    float b1v[2], b2v[2], gv[2], bv[2];
#pragma unroll
    for (int n = 0; n < 2; ++n) {
        const int c = n_base + n * 16 + cl;
        b1v[n] = b1[c]; b2v[n] = b2[c];
        gv[n]  = gam[c]; bv[n] = bet[c];
    }

    // staging geometry: 24 wave-instrs per tile (3 parts x 8 groups of 4 rows),
    // wave w owns items i = w*6 .. w*6+5.
    int s_p[6], s_row[6], s_soff[6], s_loff[6];
#pragma unroll
    for (int j = 0; j < 6; ++j) {
        const int i = w * 6 + j;
        const int p = i >> 3, g = i & 7;
        const int row = g * 4 + (lane >> 4);
        s_p[j] = p; s_row[j] = row;
        s_soff[j] = ((lane & 15) ^ (row & 7)) * 16;   // pre-swizzled source byte offset
        s_loff[j] = p * 8192 + g * 1024;              // wave-uniform LDS byte offset
    }

    const int stride = gridDim.x;
    int idxn[6];   // sender/receiver ids for this thread's stage items (next tile)

    // --- helpers (inlined) ---
#define LOAD_IDX(T)                                                              \
    {   const int tb_ = (T) * TROWS;                                             \
        _Pragma("unroll")                                                        \
        for (int j = 0; j < 6; ++j) {                                            \
            if (s_p[j] == 0)      idxn[j] = senders[tb_ + s_row[j]];             \
            else if (s_p[j] == 1) idxn[j] = receivers[tb_ + s_row[j]];           \
        }                                                                        \
    }
#define STAGE(T, BUF)                                                            \
    {   const int tb_ = (T) * TROWS;                                             \
        char* lb_ = (char*)xb[BUF];                                              \
        _Pragma("unroll")                                                        \
        for (int j = 0; j < 6; ++j) {                                            \
            if (s_p[j] == 2) {                                                   \
                if (EBF) {                                                       \
                    async16((const char*)elat_bf + ((size_t)(tb_ + s_row[j]) * 256 + s_soff[j]), \
                            lb_ + s_loff[j]);                                    \
                } else {                                                         \
                    uint4 v_ = pack8(elat32 + (size_t)(tb_ + s_row[j]) * 128 + (s_soff[j] >> 1)); \
                    *(uint4*)(lb_ + s_loff[j] + lane * 16) = v_;                 \
                }                                                                \
            } else {                                                             \
                async16((const char*)node_bf + ((size_t)idxn[j] * 256 + s_soff[j]), \
                        lb_ + s_loff[j]);                                        \
            }                                                                    \
        }                                                                        \
        if (tid < TROWS) rcv_b[BUF][tid] = receivers[tb_ + tid];                 \
    }

    // ---- prologue: stage tile0 into buf0, load idx for tile0+stride ----
    const int t0 = blockIdx.x;
    LOAD_IDX(t0);
    STAGE(t0, 0);
    { int t1 = t0 + stride; if (t1 >= NT) t1 = t0; LOAD_IDX(t1); }
    __syncthreads();   // drains prologue staging

    int cur = 0;
    for (int tile = t0; tile < NT; tile += stride) {
        const int base = tile * TROWS;
        const int tn = tile + stride;

        // ---- 1. async-stage next tile into spare buffer ----
        if (tn < NT) {
            STAGE(tn, cur ^ 1);
            int tnn = tn + stride; if (tnn >= NT) tnn = tn;
            LOAD_IDX(tnn);
        }

        // ---- 2. layer 1: [32,384] x [384,128], weights streamed from L2 ----
        f32x4 acc[2][2];
#pragma unroll
        for (int m = 0; m < 2; ++m)
#pragma unroll
            for (int n = 0; n < 2; ++n)
#pragma unroll
                for (int r = 0; r < 4; ++r) acc[m][n][r] = 0.f;

        uint4 wreg[14][2];
#pragma unroll
        for (int kb = 0; kb < 2; ++kb)
#pragma unroll
            for (int n = 0; n < 2; ++n)
                wreg[kb][n] = w1p[(kb * 8 + w * 2 + n) * 64 + lane];

#pragma unroll
        for (int kb = 0; kb < 12; ++kb) {
            if (kb + 2 < 12) {
#pragma unroll
                for (int n = 0; n < 2; ++n)
                    wreg[kb + 2][n] = w1p[((kb + 2) * 8 + w * 2 + n) * 64 + lane];
            }
            const int p = kb >> 2, k2 = kb & 3;
            bf16x8 a[2];
#pragma unroll
            for (int m = 0; m < 2; ++m) {
                const int row = m * 16 + cl;
                a[m] = __builtin_bit_cast(bf16x8,
                    ((const uint4*)xb[cur])[p * 512 + row * 16 + ((k2 * 4 + q) ^ (row & 7))]);
            }
#pragma unroll
            for (int m = 0; m < 2; ++m)
#pragma unroll
                for (int n = 0; n < 2; ++n)
                    acc[m][n] = __builtin_amdgcn_mfma_f32_16x16x32_bf16(
                        a[m], __builtin_bit_cast(bf16x8, wreg[kb][n]), acc[m][n], 0, 0, 0);
        }

        uint4 w2reg[4][2];
#pragma unroll
        for (int kb = 0; kb < 4; ++kb)
#pragma unroll
            for (int n = 0; n < 2; ++n)
                w2reg[kb][n] = w2p[(kb * 8 + w * 2 + n) * 64 + lane];

        __syncthreads();  // B: part0(cur) dead; staging loads drained here

        // relu + bias, h1 -> part0 of cur (swizzled)
        {
            __bf16* hb = (__bf16*)xb[cur];
#pragma unroll
            for (int m = 0; m < 2; ++m)
#pragma unroll
                for (int n = 0; n < 2; ++n)
#pragma unroll
                    for (int r = 0; r < 4; ++r) {
                        const int row = m * 16 + q * 4 + r;
                        const int col = n_base + n * 16 + cl;
                        hb[row * 128 + (((col >> 3) ^ (row & 7)) << 3) + (col & 7)] =
                            (__bf16)fmaxf(acc[m][n][r] + b1v[n], 0.f);
                    }
        }
        __syncthreads();  // C: h ready

        // ---- 3. layer 2: [32,128] x [128,128] ----
#pragma unroll
        for (int m = 0; m < 2; ++m)
#pragma unroll
            for (int n = 0; n < 2; ++n)
#pragma unroll
                for (int r = 0; r < 4; ++r) acc[m][n][r] = 0.f;
#pragma unroll
        for (int kb = 0; kb < 4; ++kb) {
            bf16x8 a[2];
#pragma unroll
            for (int m = 0; m < 2; ++m) {
                const int row = m * 16 + cl;
                a[m] = __builtin_bit_cast(bf16x8,
                    ((const uint4*)xb[cur])[row * 16 + ((kb * 4 + q) ^ (row & 7))]);
            }
#pragma unroll
            for (int m = 0; m < 2; ++m)
#pragma unroll
                for (int n = 0; n < 2; ++n)
                    acc[m][n] = __builtin_amdgcn_mfma_f32_16x16x32_bf16(
                        a[m], __builtin_bit_cast(bf16x8, w2reg[kb][n]), acc[m][n], 0, 0, 0);
        }

#pragma unroll
        for (int m = 0; m < 2; ++m)
#pragma unroll
            for (int n = 0; n < 2; ++n)
#pragma unroll
                for (int r = 0; r < 4; ++r)
                    acc[m][n][r] = fmaxf(acc[m][n][r] + b2v[n], 0.f);

        // ---- 4. LN stats ----
#pragma unroll
        for (int m = 0; m < 2; ++m)
#pragma unroll
            for (int r = 0; r < 4; ++r) {
                float s  = acc[m][0][r] + acc[m][1][r];
                float ss = acc[m][0][r] * acc[m][0][r] + acc[m][1][r] * acc[m][1][r];
#pragma unroll
                for (int off = 1; off < 16; off <<= 1) {
                    s  += __shfl_xor(s, off, 64);
                    ss += __shfl_xor(ss, off, 64);
                }
                if (cl == 0) part[w * 32 + m * 16 + q * 4 + r] = make_float2(s, ss);
            }
        __syncthreads();  // D
        if (tid < TROWS) {
            float s = 0.f, ss = 0.f;
#pragma unroll
            for (int ww = 0; ww < 4; ++ww) { const float2 pp = part[ww * 32 + tid]; s += pp.x; ss += pp.y; }
            const float mu = s * (1.f / 128.f);
            const float var = ss * (1.f / 128.f) - mu * mu;
            muv[tid] = mu;
            rsv[tid] = rsqrtf(var + LN_EPS);
        }
        __syncthreads();  // E

        // ---- 5. LN + eout (+elat residual from part2 of cur) + aggr atomics ----
#pragma unroll
        for (int m = 0; m < 2; ++m)
#pragma unroll
            for (int r = 0; r < 4; ++r) {
                const int row = m * 16 + q * 4 + r;
                const float mu = muv[row];
                const float rs = rsv[row];
                const int rc = rcv_b[cur][row];
                float* orow = eout + (size_t)(base + row) * 128;
#pragma unroll
                for (int n = 0; n < 2; ++n) {
                    const int col = n_base + n * 16 + cl;
                    const float ln = (acc[m][n][r] - mu) * rs * gv[n] + bv[n];
                    atomicAdd(&aggr[(size_t)rc * 128 + col], ln);
                    const float e = (float)((__bf16*)xb[cur])[8192 + row * 128 + (((col >> 3) ^ (row & 7)) << 3) + (col & 7)];
                    orow[col] = ln + e;
                }
            }
        __syncthreads();  // F: all waves done with cur before it becomes stage target
        cur ^= 1;
    }
#undef LOAD_IDX
#undef STAGE
}

// ---------------- Node MLP ----------------
__global__ __launch_bounds__(256, 4)
void node_mlp_kernel(const float* __restrict__ node, const float* __restrict__ aggr,
                     const float* __restrict__ b1, const float* __restrict__ b2,
                     const float* __restrict__ gam, const float* __restrict__ bet,
                     const uint4* __restrict__ w1p, const uint4* __restrict__ w2p,
                     float* __restrict__ nout)
{
    __shared__ __align__(16) u16 x_lds[2 * 64 * 128];
    __shared__ float2 part[256];
    __shared__ float muv[64], rsv[64];

    const int tid = threadIdx.x;
    const int w = tid >> 6;
    const int lane = tid & 63;
    const int cl = lane & 15;
    const int q = lane >> 4;
    const int n_base = w * 32;

    float b1v[2], b2v[2], gv[2], bv[2];
#pragma unroll
    for (int n = 0; n < 2; ++n) {
        const int c = n_base + n * 16 + cl;
        b1v[n] = b1[c]; b2v[n] = b2[c];
        gv[n]  = gam[c]; bv[n] = bet[c];
    }

    const int ntiles = (N_NODES + 63) / 64;
    for (int tile = blockIdx.x; tile < ntiles; tile += gridDim.x) {
        const int base = tile * 64;
        {
            const int ch = tid & 15;
            const int r0 = tid >> 4;
#pragma unroll
            for (int gp = 0; gp < 4; ++gp) {
                const int row = gp * 16 + r0;
                const int rx = row & 7;
                int gn = base + row;
                if (gn >= N_NODES) gn = N_NODES - 1;
                uint4* dst = (uint4*)x_lds + row * 16;
                dst[ch ^ rx]          = pack8(node + (size_t)gn * 128 + ch * 8);
                dst[1024 + (ch ^ rx)] = pack8(aggr + (size_t)gn * 128 + ch * 8);
            }
        }
        __syncthreads();

        f32x4 acc[4][2];
#pragma unroll
        for (int m = 0; m < 4; ++m)
#pragma unroll
            for (int n = 0; n < 2; ++n)
#pragma unroll
                for (int r = 0; r < 4; ++r) acc[m][n][r] = 0.f;
        uint4 wreg[10][2];
#pragma unroll
        for (int kb = 0; kb < 2; ++kb)
#pragma unroll
            for (int n = 0; n < 2; ++n)
                wreg[kb][n] = w1p[(kb * 8 + w * 2 + n) * 64 + lane];
#pragma unroll
        for (int kb = 0; kb < 8; ++kb) {
            if (kb + 2 < 8) {
#pragma unroll
                for (int n = 0; n < 2; ++n)
                    wreg[kb + 2][n] = w1p[((kb + 2) * 8 + w * 2 + n) * 64 + lane];
            }
            const int p = kb >> 2, k2 = kb & 3;
            bf16x8 a[4];
#pragma unroll
            for (int m = 0; m < 4; ++m) {
                const int row = m * 16 + cl;
                a[m] = __builtin_bit_cast(bf16x8,
                    ((const uint4*)x_lds)[p * 1024 + row * 16 + ((k2 * 4 + q) ^ (row & 7))]);
            }
#pragma unroll
            for (int m = 0; m < 4; ++m)
#pragma unroll
                for (int n = 0; n < 2; ++n)
                    acc[m][n] = __builtin_amdgcn_mfma_f32_16x16x32_bf16(
                        a[m], __builtin_bit_cast(bf16x8, wreg[kb][n]), acc[m][n], 0, 0, 0);
        }
        uint4 w2reg[4][2];
#pragma unroll
        for (int kb = 0; kb < 4; ++kb)
#pragma unroll
            for (int n = 0; n < 2; ++n)
                w2reg[kb][n] = w2p[(kb * 8 + w * 2 + n) * 64 + lane];
        __syncthreads();
        {
            __bf16* hb = (__bf16*)(x_lds + 8192);
#pragma unroll
            for (int m = 0; m < 4; ++m)
#pragma unroll
                for (int n = 0; n < 2; ++n)
#pragma unroll
                    for (int r = 0; r < 4; ++r) {
                        const int row = m * 16 + q * 4 + r;
                        const int col = n_base + n * 16 + cl;
                        hb[row * 128 + (((col >> 3) ^ (row & 7)) << 3) + (col & 7)] =
                            (__bf16)fmaxf(acc[m][n][r] + b1v[n], 0.f);
                    }
        }
        __syncthreads();
#pragma unroll
        for (int m = 0; m < 4; ++m)
#pragma unroll
            for (int n = 0; n < 2; ++n)
#pragma unroll
                for (int r = 0; r < 4; ++r) acc[m][n][r] = 0.f;
#pragma unroll
        for (int kb = 0; kb < 4; ++kb) {
            bf16x8 a[4];
#pragma unroll
            for (int m = 0; m < 4; ++m) {
                const int row = m * 16 + cl;
                a[m] = __builtin_bit_cast(bf16x8,
                    ((const uint4*)x_lds)[1024 + row * 16 + ((kb * 4 + q) ^ (row & 7))]);
            }
#pragma unroll
            for (int m = 0; m < 4; ++m)
#pragma unroll
                for (int n = 0; n < 2; ++n)
                    acc[m][n] = __builtin_amdgcn_mfma_f32_16x16x32_bf16(
                        a[m], __builtin_bit_cast(bf16x8, w2reg[kb][n]), acc[m][n], 0, 0, 0);
        }
#pragma unroll
        for (int m = 0; m < 4; ++m)
#pragma unroll
            for (int n = 0; n < 2; ++n)
#pragma unroll
                for (int r = 0; r < 4; ++r)
                    acc[m][n][r] = fmaxf(acc[m][n][r] + b2v[n], 0.f);
#pragma unroll
        for (int m = 0; m < 4; ++m)
#pragma unroll
            for (int r = 0; r < 4; ++r) {
                float s  = acc[m][0][r] + acc[m][1][r];
                float ss = acc[m][0][r] * acc[m][0][r] + acc[m][1][r] * acc[m][1][r];
#pragma unroll
                for (int off = 1; off < 16; off <<= 1) {
                    s  += __shfl_xor(s, off, 64);
                    ss += __shfl_xor(ss, off, 64);
                }
                if (cl == 0) part[w * 64 + m * 16 + q * 4 + r] = make_float2(s, ss);
            }
        __syncthreads();
        if (tid < 64) {
            float s = 0.f, ss = 0.f;
#pragma unroll
            for (int ww = 0; ww < 4; ++ww) { const float2 pp = part[ww * 64 + tid]; s += pp.x; ss += pp.y; }
            const float mu = s * (1.f / 128.f);
            const float var = ss * (1.f / 128.f) - mu * mu;
            muv[tid] = mu;
            rsv[tid] = rsqrtf(var + LN_EPS);
        }
        __syncthreads();
#pragma unroll
        for (int m = 0; m < 4; ++m)
#pragma unroll
            for (int r = 0; r < 4; ++r) {
                const int row = m * 16 + q * 4 + r;
                if (base + row < N_NODES) {
                    const float mu = muv[row];
                    const float rs = rsv[row];
                    float* orow = nout + (size_t)(base + row) * 128;
#pragma unroll
                    for (int n = 0; n < 2; ++n) {
                        const int col = n_base + n * 16 + cl;
                        const float ln = (acc[m][n][r] - mu) * rs * gv[n] + bv[n];
                        const float e = (float)((__bf16*)x_lds)[row * 128 + (((col >> 3) ^ (row & 7)) << 3) + (col & 7)];
                        orow[col] = ln + e;
                    }
                }
            }
        __syncthreads();
    }
}

extern "C" void kernel_launch(void* const* d_in, const int* in_sizes, int n_in,
                              void* d_out, int out_size, void* d_ws, size_t ws_size,
                              hipStream_t stream) {
    (void)in_sizes; (void)n_in; (void)out_size;
    const float* node = (const float*)d_in[0];
    const float* elat = (const float*)d_in[1];
    const int* senders = (const int*)d_in[2];
    const int* receivers = (const int*)d_in[3];
    const float* me_w1 = (const float*)d_in[4];
    const float* me_b1 = (const float*)d_in[5];
    const float* me_w2 = (const float*)d_in[6];
    const float* me_b2 = (const float*)d_in[7];
    const float* me_g  = (const float*)d_in[8];
    const float* me_be = (const float*)d_in[9];
    const float* nf_w1 = (const float*)d_in[10];
    const float* nf_b1 = (const float*)d_in[11];
    const float* nf_w2 = (const float*)d_in[12];
    const float* nf_b2 = (const float*)d_in[13];
    const float* nf_g  = (const float*)d_in[14];
    const float* nf_be = (const float*)d_in[15];

    float* out_nodes = (float*)d_out;
    float* out_edges = out_nodes + (size_t)N_NODES * 128;

    // d_out scratch (free until node_mlp, which runs last): bf16 node table
    u16* node_bf = (u16*)d_out;                                      // 12.8 MB

    // ws layout
    char* ws = (char*)d_ws;
    const size_t off_aggr   = 0;
    const size_t off_wpack  = off_aggr  + (size_t)N_NODES * 128 * sizeof(float);  // 25,600,000
    const size_t off_elat   = off_wpack + 14336 * sizeof(uint4);                  // 25,829,376
    const size_t need_min   = off_elat;
    const size_t need_ebf   = off_elat + (size_t)N_EDGES * 128 * sizeof(u16);     // ~230.6 MB
    if (ws_size < need_min) return;

    float* aggr    = (float*)(ws + off_aggr);
    uint4* wpack   = (uint4*)(ws + off_wpack);
    u16*   elat_bf = (u16*)(ws + off_elat);
    const bool ebf = (ws_size >= need_ebf);

    hipMemsetAsync(aggr, 0, (size_t)N_NODES * 128 * sizeof(float), stream);
    pack_weights<<<56, 256, 0, stream>>>(me_w1, me_w2, nf_w1, nf_w2, wpack);
    convert_node<<<3125, 256, 0, stream>>>(node, (uint4*)node_bf);

    if (ebf) {
        convert_elat<<<50000, 256, 0, stream>>>(elat, (uint4*)elat_bf);
        edge_async<1><<<768, 256, 0, stream>>>(node_bf, elat, elat_bf, senders, receivers,
                                               me_b1, me_b2, me_g, me_be,
                                               wpack, wpack + 6144,
                                               out_edges, aggr);
    } else {
        edge_async<0><<<768, 256, 0, stream>>>(node_bf, elat, elat_bf, senders, receivers,
                                               me_b1, me_b2, me_g, me_be,
                                               wpack, wpack + 6144,
                                               out_edges, aggr);
    }
    node_mlp_kernel<<<782, 256, 0, stream>>>(node, aggr,
                                             nf_b1, nf_b2, nf_g, nf_be,
                                             wpack + 8192, wpack + 12288,
                                             out_nodes);
}

// Round 10
// 1135.194 us; speedup vs baseline: 1.4441x; 1.1185x over previous
//
#include <hip/hip_runtime.h>
#include <stdint.h>

typedef unsigned short u16;
typedef __bf16 bf16x8 __attribute__((ext_vector_type(8)));
typedef float f32x4 __attribute__((ext_vector_type(4)));

#define N_NODES 50000
#define N_EDGES 800000
#define NTILES  (N_EDGES / 64)   // 12500
#define LN_EPS  1e-5f

__device__ __forceinline__ u16 f2bfu(float f) {
    __bf16 b = (__bf16)f;
    return __builtin_bit_cast(u16, b);
}
__device__ __forceinline__ float bfu2f(u16 u) {
    return (float)__builtin_bit_cast(__bf16, u);
}
// pack 8 consecutive f32 -> uint4 of 8 bf16
__device__ __forceinline__ uint4 pack8(const float* __restrict__ p) {
    const float4 f0 = ((const float4*)p)[0];
    const float4 f1 = ((const float4*)p)[1];
    union { __bf16 b[8]; uint4 q; } t;
    t.b[0] = (__bf16)f0.x; t.b[1] = (__bf16)f0.y; t.b[2] = (__bf16)f0.z; t.b[3] = (__bf16)f0.w;
    t.b[4] = (__bf16)f1.x; t.b[5] = (__bf16)f1.y; t.b[6] = (__bf16)f1.z; t.b[7] = (__bf16)f1.w;
    return t.q;
}

// ---------------- weight pre-pack (fragment-contiguous bf16) ----------------
__global__ void pack_weights(const float* __restrict__ w1e, const float* __restrict__ w2e,
                             const float* __restrict__ w1n, const float* __restrict__ w2n,
                             uint4* __restrict__ out)
{
    const int t = blockIdx.x * 256 + threadIdx.x;
    const float* W; int idx;
    if (t < 6144)       { W = w1e; idx = t; }
    else if (t < 8192)  { W = w2e; idx = t - 6144; }
    else if (t < 12288) { W = w1n; idx = t - 8192; }
    else                { W = w2n; idx = t - 12288; }
    const int lane = idx & 63;
    const int col16 = (idx >> 6) & 7;
    const int kb = idx >> 9;
    const int row0 = kb * 32 + (lane >> 4) * 8;
    const int col = col16 * 16 + (lane & 15);
    union { __bf16 b[8]; uint4 q; } v;
#pragma unroll
    for (int j = 0; j < 8; ++j) v.b[j] = (__bf16)W[(size_t)(row0 + j) * 128 + col];
    out[t] = v.q;
}

// ---------------- node table f32 -> bf16 ----------------
__global__ void convert_node(const float* __restrict__ node, uint4* __restrict__ node_bf) {
    const int idx = blockIdx.x * 256 + threadIdx.x;          // 800,000 chunks
    node_bf[idx] = pack8(node + (size_t)idx * 8);
}

// ---------------- counting sort by receiver ----------------
__global__ void hist_kernel(const int* __restrict__ receivers, int* __restrict__ cnt) {
    const int e = blockIdx.x * 256 + threadIdx.x;
    if (e < N_EDGES) atomicAdd(&cnt[receivers[e]], 1);
}
#define SCAN_NB 196
__global__ void scan1(const int* __restrict__ cnt, int* __restrict__ bsum) {
    __shared__ int wsum[4];
    const int i = blockIdx.x * 256 + threadIdx.x;
    int v = (i < N_NODES) ? cnt[i] : 0;
#pragma unroll
    for (int off = 1; off < 64; off <<= 1) v += __shfl_xor(v, off, 64);
    if ((threadIdx.x & 63) == 0) wsum[threadIdx.x >> 6] = v;
    __syncthreads();
    if (threadIdx.x == 0) bsum[blockIdx.x] = wsum[0] + wsum[1] + wsum[2] + wsum[3];
}
__global__ void scan2(const int* __restrict__ bsum, int* __restrict__ boff) {
    __shared__ int s[256];
    const int t = threadIdx.x;
    const int v = (t < SCAN_NB) ? bsum[t] : 0;
    s[t] = v; __syncthreads();
    for (int off = 1; off < 256; off <<= 1) {
        const int u = (t >= off) ? s[t - off] : 0;
        __syncthreads(); s[t] += u; __syncthreads();
    }
    if (t < SCAN_NB) boff[t] = s[t] - v;
}
__global__ void scan3(const int* __restrict__ cnt, const int* __restrict__ boff,
                      int* __restrict__ cursor) {
    __shared__ int s[256];
    const int i = blockIdx.x * 256 + threadIdx.x;
    const int t = threadIdx.x;
    const int v = (i < N_NODES) ? cnt[i] : 0;
    s[t] = v; __syncthreads();
    for (int off = 1; off < 256; off <<= 1) {
        const int u = (t >= off) ? s[t - off] : 0;
        __syncthreads(); s[t] += u; __syncthreads();
    }
    if (i < N_NODES) cursor[i] = boff[blockIdx.x] + s[t] - v;
}
__global__ void scatter_kernel(const int* __restrict__ senders, const int* __restrict__ receivers,
                               int* __restrict__ cursor,
                               int* __restrict__ sorted_eid, int* __restrict__ pos_of,
                               int* __restrict__ snd_sorted, int* __restrict__ rcv_sorted) {
    const int e = blockIdx.x * 256 + threadIdx.x;
    if (e < N_EDGES) {
        const int rc = receivers[e];
        const int pos = atomicAdd(&cursor[rc], 1);
        sorted_eid[pos] = e;
        pos_of[e] = pos;
        snd_sorted[pos] = senders[e];
        rcv_sorted[pos] = rc;
    }
}
// elat f32 sequential read -> bf16 row at receiver-sorted position (scatter write)
__global__ void permute_elat(const float* __restrict__ elat, const int* __restrict__ pos_of,
                             uint4* __restrict__ elat_s) {
    const int idx = blockIdx.x * 256 + threadIdx.x;   // 12.8M chunks
    const int e = idx >> 4, ch = idx & 15;
    const int p = pos_of[e];
    elat_s[(size_t)p * 16 + ch] = pack8(elat + (size_t)e * 128 + ch * 8);
}

// ---------------- HS = node@W1a, HR = node@W1b (bf16 out, one pass) ----------------
__global__ void proj_nodes(const u16* __restrict__ node_bf, const uint4* __restrict__ w1p,
                           uint4* __restrict__ HS, uint4* __restrict__ HR)
{
    __shared__ __align__(16) u16 x[64 * 128];        // 16 KB staging
    __shared__ __align__(16) u16 hout[2 * 64 * 128]; // 32 KB: S | R
    const int tid = threadIdx.x;
    const int w = tid >> 6, lane = tid & 63, cl = lane & 15, q = lane >> 4;
    const int n_base = w * 32;
    const int base = blockIdx.x * 64;
    const int ch = tid & 15;
#pragma unroll
    for (int k = 0; k < 4; ++k) {
        const int item = tid + k * 256, row = item >> 4;
        int gn = base + row; if (gn >= N_NODES) gn = N_NODES - 1;
        ((uint4*)x)[row * 16 + (ch ^ (row & 7))] = ((const uint4*)node_bf)[(size_t)gn * 16 + ch];
    }
    uint4 wfS[4][2], wfR[4][2];
#pragma unroll
    for (int kb = 0; kb < 4; ++kb)
#pragma unroll
        for (int n = 0; n < 2; ++n) {
            wfS[kb][n] = w1p[(kb * 8 + w * 2 + n) * 64 + lane];
            wfR[kb][n] = w1p[((kb + 4) * 8 + w * 2 + n) * 64 + lane];
        }
    __syncthreads();
    f32x4 aS[4][2], aR[4][2];
#pragma unroll
    for (int m = 0; m < 4; ++m)
#pragma unroll
        for (int n = 0; n < 2; ++n)
#pragma unroll
            for (int r = 0; r < 4; ++r) { aS[m][n][r] = 0.f; aR[m][n][r] = 0.f; }
#pragma unroll
    for (int kb = 0; kb < 4; ++kb) {
        bf16x8 a[4];
#pragma unroll
        for (int m = 0; m < 4; ++m) {
            const int row = m * 16 + cl;
            a[m] = __builtin_bit_cast(bf16x8, ((const uint4*)x)[row * 16 + ((kb * 4 + q) ^ (row & 7))]);
        }
#pragma unroll
        for (int m = 0; m < 4; ++m)
#pragma unroll
            for (int n = 0; n < 2; ++n) {
                aS[m][n] = __builtin_amdgcn_mfma_f32_16x16x32_bf16(a[m], __builtin_bit_cast(bf16x8, wfS[kb][n]), aS[m][n], 0, 0, 0);
                aR[m][n] = __builtin_amdgcn_mfma_f32_16x16x32_bf16(a[m], __builtin_bit_cast(bf16x8, wfR[kb][n]), aR[m][n], 0, 0, 0);
            }
    }
#pragma unroll
    for (int m = 0; m < 4; ++m)
#pragma unroll
        for (int n = 0; n < 2; ++n)
#pragma unroll
            for (int r = 0; r < 4; ++r) {
                const int row = m * 16 + q * 4 + r;
                const int col = n_base + n * 16 + cl;
                hout[row * 128 + col]        = f2bfu(aS[m][n][r]);
                hout[8192 + row * 128 + col] = f2bfu(aR[m][n][r]);
            }
    __syncthreads();
#pragma unroll
    for (int k = 0; k < 4; ++k) {
        const int item = tid + k * 256, row = item >> 4;
        const int gn = base + row;
        if (gn < N_NODES) {
            HS[(size_t)gn * 16 + ch] = ((const uint4*)hout)[row * 16 + ch];
            HR[(size_t)gn * 16 + ch] = ((const uint4*)hout)[1024 + row * 16 + ch];
        }
    }
}

// ---------------- Edge kernel: h1 = relu(HS[s]+HR[r]+elat@W1c+b1); L2; LN; reduce ----
// LDS: x (elat bf16 swz, then h1 overlay, 16KB) + lnf (hsum then ln, f32 stride 132).
// W1c and W2 fragments live in registers, loaded ONCE per block (no per-tile refetch).
__global__ __launch_bounds__(256, 3)
void edge_sum(const u16* __restrict__ HS, const u16* __restrict__ HR,
              const u16* __restrict__ elat_s,
              const int* __restrict__ snd_sorted, const int* __restrict__ rcv_sorted,
              const int* __restrict__ sorted_eid,
              const float* __restrict__ b1, const float* __restrict__ b2,
              const float* __restrict__ gam, const float* __restrict__ bet,
              const uint4* __restrict__ w1p, const uint4* __restrict__ w2p,
              float* __restrict__ eout, float* __restrict__ aggr)
{
    __shared__ __align__(16) u16 x_lds[64 * 128];    // 16 KB
    __shared__ float lnf[64 * 132];                  // 33.8 KB (pad 132 vs bank conflicts)
    __shared__ int rcv_s[64], eid_s[64];
    __shared__ float2 part[256];
    __shared__ float muv[64], rsv[64];

    const int tid = threadIdx.x;
    const int w = tid >> 6, lane = tid & 63, cl = lane & 15, q = lane >> 4;
    const int n_base = w * 32;
    const int ch = tid & 15;

    float b1r[8];
#pragma unroll
    for (int j = 0; j < 8; ++j) b1r[j] = b1[ch * 8 + j];
    uint4 w1c[4][2], w2r[4][2];
#pragma unroll
    for (int kb = 0; kb < 4; ++kb)
#pragma unroll
        for (int n = 0; n < 2; ++n) {
            w1c[kb][n] = w1p[((kb + 8) * 8 + w * 2 + n) * 64 + lane];
            w2r[kb][n] = w2p[(kb * 8 + w * 2 + n) * 64 + lane];
        }
    float b2v[2], gv[2], bv[2];
#pragma unroll
    for (int n = 0; n < 2; ++n) {
        const int c = n_base + n * 16 + cl;
        b2v[n] = b2[c]; gv[n] = gam[c]; bv[n] = bet[c];
    }

    // XCD-chunked contiguous sorted ranges (receiver + aggr locality per XCD L2)
    const int nchunk = gridDim.x;
    const int chunk = (blockIdx.x & 7) * (nchunk >> 3) + (blockIdx.x >> 3);
    const int t_lo = (int)(((long long)chunk * NTILES) / nchunk);
    const int t_hi = (int)(((long long)(chunk + 1) * NTILES) / nchunk);

    for (int tile = t_lo; tile < t_hi; ++tile) {
        const int base = tile * 64;

        // ---- phase 1: stage elat + hsum = HS[s]+HR[r]+b1 ----
#pragma unroll
        for (int k = 0; k < 4; ++k) {
            const int item = tid + k * 256, row = item >> 4;
            const int p = base + row;
            const int sn = snd_sorted[p];
            const int rc = rcv_sorted[p];
            if (ch == 0) { rcv_s[row] = rc; eid_s[row] = sorted_eid[p]; }
            ((uint4*)x_lds)[row * 16 + (ch ^ (row & 7))] = ((const uint4*)elat_s)[(size_t)p * 16 + ch];
            union { uint4 q; u16 u[8]; } hs, hr;
            hs.q = ((const uint4*)HS)[(size_t)sn * 16 + ch];
            hr.q = ((const uint4*)HR)[(size_t)rc * 16 + ch];
#pragma unroll
            for (int j = 0; j < 8; ++j)
                lnf[row * 132 + ch * 8 + j] = bfu2f(hs.u[j]) + bfu2f(hr.u[j]) + b1r[j];
        }
        __syncthreads();  // A

        // ---- phase 2: elat@W1c (reg weights) + hsum, relu; grab residual ----
        f32x4 acc[4][2];
#pragma unroll
        for (int m = 0; m < 4; ++m)
#pragma unroll
            for (int n = 0; n < 2; ++n)
#pragma unroll
                for (int r = 0; r < 4; ++r) acc[m][n][r] = 0.f;
#pragma unroll
        for (int kb = 0; kb < 4; ++kb) {
            bf16x8 a[4];
#pragma unroll
            for (int m = 0; m < 4; ++m) {
                const int row = m * 16 + cl;
                a[m] = __builtin_bit_cast(bf16x8, ((const uint4*)x_lds)[row * 16 + ((kb * 4 + q) ^ (row & 7))]);
            }
#pragma unroll
            for (int m = 0; m < 4; ++m)
#pragma unroll
                for (int n = 0; n < 2; ++n)
                    acc[m][n] = __builtin_amdgcn_mfma_f32_16x16x32_bf16(a[m], __builtin_bit_cast(bf16x8, w1c[kb][n]), acc[m][n], 0, 0, 0);
        }
        unsigned int rp[4][2][2];   // packed bf16 residual (elat) at C-positions
#pragma unroll
        for (int m = 0; m < 4; ++m)
#pragma unroll
            for (int n = 0; n < 2; ++n) {
#pragma unroll
                for (int r = 0; r < 4; ++r) {
                    const int row = m * 16 + q * 4 + r;
                    const int col = n_base + n * 16 + cl;
                    acc[m][n][r] = fmaxf(acc[m][n][r] + lnf[row * 132 + col], 0.f);
                }
#pragma unroll
                for (int rr = 0; rr < 2; ++rr) {
                    const int r0 = rr * 2;
                    const int row0 = m * 16 + q * 4 + r0;
                    const int row1 = row0 + 1;
                    const int col = n_base + n * 16 + cl;
                    const unsigned int lo = x_lds[row0 * 128 + (((col >> 3) ^ (row0 & 7)) << 3) + (col & 7)];
                    const unsigned int hi = x_lds[row1 * 128 + (((col >> 3) ^ (row1 & 7)) << 3) + (col & 7)];
                    rp[m][n][rr] = lo | (hi << 16);
                }
            }
        __syncthreads();  // B: x (elat) + lnf(hsum) dead

        // h1 -> x region (swizzled bf16)
#pragma unroll
        for (int m = 0; m < 4; ++m)
#pragma unroll
            for (int n = 0; n < 2; ++n)
#pragma unroll
                for (int r = 0; r < 4; ++r) {
                    const int row = m * 16 + q * 4 + r;
                    const int col = n_base + n * 16 + cl;
                    x_lds[row * 128 + (((col >> 3) ^ (row & 7)) << 3) + (col & 7)] = f2bfu(acc[m][n][r]);
                }
        __syncthreads();  // C

        // ---- phase 3: layer 2 (reg weights) ----
#pragma unroll
        for (int m = 0; m < 4; ++m)
#pragma unroll
            for (int n = 0; n < 2; ++n)
#pragma unroll
                for (int r = 0; r < 4; ++r) acc[m][n][r] = 0.f;
#pragma unroll
        for (int kb = 0; kb < 4; ++kb) {
            bf16x8 a[4];
#pragma unroll
            for (int m = 0; m < 4; ++m) {
                const int row = m * 16 + cl;
                a[m] = __builtin_bit_cast(bf16x8, ((const uint4*)x_lds)[row * 16 + ((kb * 4 + q) ^ (row & 7))]);
            }
#pragma unroll
            for (int m = 0; m < 4; ++m)
#pragma unroll
                for (int n = 0; n < 2; ++n)
                    acc[m][n] = __builtin_amdgcn_mfma_f32_16x16x32_bf16(a[m], __builtin_bit_cast(bf16x8, w2r[kb][n]), acc[m][n], 0, 0, 0);
        }
#pragma unroll
        for (int m = 0; m < 4; ++m)
#pragma unroll
            for (int n = 0; n < 2; ++n)
#pragma unroll
                for (int r = 0; r < 4; ++r)
                    acc[m][n][r] = fmaxf(acc[m][n][r] + b2v[n], 0.f);

        // ---- LN stats ----
#pragma unroll
        for (int m = 0; m < 4; ++m)
#pragma unroll
            for (int r = 0; r < 4; ++r) {
                float s  = acc[m][0][r] + acc[m][1][r];
                float ss = acc[m][0][r] * acc[m][0][r] + acc[m][1][r] * acc[m][1][r];
#pragma unroll
                for (int off = 1; off < 16; off <<= 1) {
                    s  += __shfl_xor(s, off, 64);
                    ss += __shfl_xor(ss, off, 64);
                }
                if (cl == 0) part[w * 64 + m * 16 + q * 4 + r] = make_float2(s, ss);
            }
        __syncthreads();  // D
        if (tid < 64) {
            float s = 0.f, ss = 0.f;
#pragma unroll
            for (int ww = 0; ww < 4; ++ww) { const float2 pp = part[ww * 64 + tid]; s += pp.x; ss += pp.y; }
            const float mu = s * (1.f / 128.f);
            const float var = ss * (1.f / 128.f) - mu * mu;
            muv[tid] = mu;
            rsv[tid] = rsqrtf(var + LN_EPS);
        }
        __syncthreads();  // E

        // ---- phase 4: LN -> lnf(f32) + eout (ln + elat residual) ----
#pragma unroll
        for (int m = 0; m < 4; ++m)
#pragma unroll
            for (int r = 0; r < 4; ++r) {
                const int row = m * 16 + q * 4 + r;
                const float mu = muv[row];
                const float rs = rsv[row];
                float* orow = eout + (size_t)eid_s[row] * 128;
#pragma unroll
                for (int n = 0; n < 2; ++n) {
                    const int col = n_base + n * 16 + cl;
                    const float ln = (acc[m][n][r] - mu) * rs * gv[n] + bv[n];
                    lnf[row * 132 + col] = ln;
                    const float resv = bfu2f((u16)(rp[m][n][r >> 1] >> ((r & 1) * 16)));
                    orow[col] = ln + resv;
                }
            }
        __syncthreads();  // G

        // ---- phase 5: segment reduce over sorted receivers ----
        {
            const int c = tid & 127;
            const int h = tid >> 7;
            const int rstart = h * 32, rend = rstart + 32;
            float sacc = 0.f; int flushed = 0;
#pragma unroll 1
            for (int r = rstart; r < rend; ++r) {
                sacc += lnf[r * 132 + c];
                const int rc = rcv_s[r];
                const bool last = (r == 63);
                const bool bnd = last || (rc != rcv_s[r + 1]);
                if (bnd) {
                    float* dst = &aggr[(size_t)rc * 128 + c];
                    if (!last && flushed) *dst = sacc;   // interior segment: sole writer
                    else atomicAdd(dst, sacc);
                    sacc = 0.f; flushed = 1;
                }
            }
            if (sacc != 0.f)
                atomicAdd(&aggr[(size_t)rcv_s[rend - 1] * 128 + c], sacc);
        }
        __syncthreads();  // F
    }
}

// ---------------- Node MLP (unchanged) ----------------
__global__ __launch_bounds__(256, 4)
void node_mlp_kernel(const float* __restrict__ node, const float* __restrict__ aggr,
                     const float* __restrict__ b1, const float* __restrict__ b2,
                     const float* __restrict__ gam, const float* __restrict__ bet,
                     const uint4* __restrict__ w1p, const uint4* __restrict__ w2p,
                     float* __restrict__ nout)
{
    __shared__ __align__(16) u16 x_lds[2 * 64 * 128];
    __shared__ float2 part[256];
    __shared__ float muv[64], rsv[64];

    const int tid = threadIdx.x;
    const int w = tid >> 6, lane = tid & 63, cl = lane & 15, q = lane >> 4;
    const int n_base = w * 32;

    float b1v[2], b2v[2], gv[2], bv[2];
#pragma unroll
    for (int n = 0; n < 2; ++n) {
        const int c = n_base + n * 16 + cl;
        b1v[n] = b1[c]; b2v[n] = b2[c];
        gv[n]  = gam[c]; bv[n] = bet[c];
    }

    const int ntiles = (N_NODES + 63) / 64;
    for (int tile = blockIdx.x; tile < ntiles; tile += gridDim.x) {
        const int base = tile * 64;
        {
            const int ch = tid & 15;
            const int r0 = tid >> 4;
#pragma unroll
            for (int gp = 0; gp < 4; ++gp) {
                const int row = gp * 16 + r0;
                const int rx = row & 7;
                int gn = base + row;
                if (gn >= N_NODES) gn = N_NODES - 1;
                uint4* dst = (uint4*)x_lds + row * 16;
                dst[ch ^ rx]          = pack8(node + (size_t)gn * 128 + ch * 8);
                dst[1024 + (ch ^ rx)] = pack8(aggr + (size_t)gn * 128 + ch * 8);
            }
        }
        __syncthreads();

        f32x4 acc[4][2];
#pragma unroll
        for (int m = 0; m < 4; ++m)
#pragma unroll
            for (int n = 0; n < 2; ++n)
#pragma unroll
                for (int r = 0; r < 4; ++r) acc[m][n][r] = 0.f;
        uint4 wreg[10][2];
#pragma unroll
        for (int kb = 0; kb < 2; ++kb)
#pragma unroll
            for (int n = 0; n < 2; ++n)
                wreg[kb][n] = w1p[(kb * 8 + w * 2 + n) * 64 + lane];
#pragma unroll
        for (int kb = 0; kb < 8; ++kb) {
            if (kb + 2 < 8) {
#pragma unroll
                for (int n = 0; n < 2; ++n)
                    wreg[kb + 2][n] = w1p[((kb + 2) * 8 + w * 2 + n) * 64 + lane];
            }
            const int p = kb >> 2, k2 = kb & 3;
            bf16x8 a[4];
#pragma unroll
            for (int m = 0; m < 4; ++m) {
                const int row = m * 16 + cl;
                a[m] = __builtin_bit_cast(bf16x8,
                    ((const uint4*)x_lds)[p * 1024 + row * 16 + ((k2 * 4 + q) ^ (row & 7))]);
            }
#pragma unroll
            for (int m = 0; m < 4; ++m)
#pragma unroll
                for (int n = 0; n < 2; ++n)
                    acc[m][n] = __builtin_amdgcn_mfma_f32_16x16x32_bf16(
                        a[m], __builtin_bit_cast(bf16x8, wreg[kb][n]), acc[m][n], 0, 0, 0);
        }
        uint4 w2reg[4][2];
#pragma unroll
        for (int kb = 0; kb < 4; ++kb)
#pragma unroll
            for (int n = 0; n < 2; ++n)
                w2reg[kb][n] = w2p[(kb * 8 + w * 2 + n) * 64 + lane];
        __syncthreads();
        {
            __bf16* hb = (__bf16*)(x_lds + 8192);
#pragma unroll
            for (int m = 0; m < 4; ++m)
#pragma unroll
                for (int n = 0; n < 2; ++n)
#pragma unroll
                    for (int r = 0; r < 4; ++r) {
                        const int row = m * 16 + q * 4 + r;
                        const int col = n_base + n * 16 + cl;
                        hb[row * 128 + (((col >> 3) ^ (row & 7)) << 3) + (col & 7)] =
                            (__bf16)fmaxf(acc[m][n][r] + b1v[n], 0.f);
                    }
        }
        __syncthreads();
#pragma unroll
        for (int m = 0; m < 4; ++m)
#pragma unroll
            for (int n = 0; n < 2; ++n)
#pragma unroll
                for (int r = 0; r < 4; ++r) acc[m][n][r] = 0.f;
#pragma unroll
        for (int kb = 0; kb < 4; ++kb) {
            bf16x8 a[4];
#pragma unroll
            for (int m = 0; m < 4; ++m) {
                const int row = m * 16 + cl;
                a[m] = __builtin_bit_cast(bf16x8,
                    ((const uint4*)x_lds)[1024 + row * 16 + ((kb * 4 + q) ^ (row & 7))]);
            }
#pragma unroll
            for (int m = 0; m < 4; ++m)
#pragma unroll
                for (int n = 0; n < 2; ++n)
                    acc[m][n] = __builtin_amdgcn_mfma_f32_16x16x32_bf16(
                        a[m], __builtin_bit_cast(bf16x8, w2reg[kb][n]), acc[m][n], 0, 0, 0);
        }
#pragma unroll
        for (int m = 0; m < 4; ++m)
#pragma unroll
            for (int n = 0; n < 2; ++n)
#pragma unroll
                for (int r = 0; r < 4; ++r)
                    acc[m][n][r] = fmaxf(acc[m][n][r] + b2v[n], 0.f);
#pragma unroll
        for (int m = 0; m < 4; ++m)
#pragma unroll
            for (int r = 0; r < 4; ++r) {
                float s  = acc[m][0][r] + acc[m][1][r];
                float ss = acc[m][0][r] * acc[m][0][r] + acc[m][1][r] * acc[m][1][r];
#pragma unroll
                for (int off = 1; off < 16; off <<= 1) {
                    s  += __shfl_xor(s, off, 64);
                    ss += __shfl_xor(ss, off, 64);
                }
                if (cl == 0) part[w * 64 + m * 16 + q * 4 + r] = make_float2(s, ss);
            }
        __syncthreads();
        if (tid < 64) {
            float s = 0.f, ss = 0.f;
#pragma unroll
            for (int ww = 0; ww < 4; ++ww) { const float2 pp = part[ww * 64 + tid]; s += pp.x; ss += pp.y; }
            const float mu = s * (1.f / 128.f);
            const float var = ss * (1.f / 128.f) - mu * mu;
            muv[tid] = mu;
            rsv[tid] = rsqrtf(var + LN_EPS);
        }
        __syncthreads();
#pragma unroll
        for (int m = 0; m < 4; ++m)
#pragma unroll
            for (int r = 0; r < 4; ++r) {
                const int row = m * 16 + q * 4 + r;
                if (base + row < N_NODES) {
                    const float mu = muv[row];
                    const float rs = rsv[row];
                    float* orow = nout + (size_t)(base + row) * 128;
#pragma unroll
                    for (int n = 0; n < 2; ++n) {
                        const int col = n_base + n * 16 + cl;
                        const float ln = (acc[m][n][r] - mu) * rs * gv[n] + bv[n];
                        const float e = (float)((__bf16*)x_lds)[row * 128 + (((col >> 3) ^ (row & 7)) << 3) + (col & 7)];
                        orow[col] = ln + e;
                    }
                }
            }
        __syncthreads();
    }
}

extern "C" void kernel_launch(void* const* d_in, const int* in_sizes, int n_in,
                              void* d_out, int out_size, void* d_ws, size_t ws_size,
                              hipStream_t stream) {
    (void)in_sizes; (void)n_in; (void)out_size;
    const float* node = (const float*)d_in[0];
    const float* elat = (const float*)d_in[1];
    const int* senders = (const int*)d_in[2];
    const int* receivers = (const int*)d_in[3];
    const float* me_w1 = (const float*)d_in[4];
    const float* me_b1 = (const float*)d_in[5];
    const float* me_w2 = (const float*)d_in[6];
    const float* me_b2 = (const float*)d_in[7];
    const float* me_g  = (const float*)d_in[8];
    const float* me_be = (const float*)d_in[9];
    const float* nf_w1 = (const float*)d_in[10];
    const float* nf_b1 = (const float*)d_in[11];
    const float* nf_w2 = (const float*)d_in[12];
    const float* nf_b2 = (const float*)d_in[13];
    const float* nf_g  = (const float*)d_in[14];
    const float* nf_be = (const float*)d_in[15];

    float* out_nodes = (float*)d_out;
    float* out_edges = out_nodes + (size_t)N_NODES * 128;

    // d_out scratch (out_nodes region; free until node_mlp, which runs last):
    char* ob = (char*)d_out;
    u16* node_bf    = (u16*)ob;                    // 12.8 MB
    int* sorted_eid = (int*)(ob + 12800000);       // 3.2 MB
    int* pos_of     = (int*)(ob + 16000000);       // 3.2 MB
    int* snd_sorted = (int*)(ob + 19200000);       // 3.2 MB
    int* rcv_sorted = (int*)(ob + 22400000);       // 3.2 MB  (= 25.6 MB exactly)

    // ws layout (16B-aligned offsets)
    char* ws = (char*)d_ws;
    const size_t off_aggr   = 0;
    const size_t off_wpack  = off_aggr   + (size_t)N_NODES * 128 * sizeof(float); // 25,600,000
    const size_t off_cnt    = off_wpack  + 14336 * sizeof(uint4);                 // 25,829,376
    const size_t off_cursor = off_cnt    + (size_t)N_NODES * sizeof(int);         // 26,029,376
    const size_t off_scan   = off_cursor + (size_t)N_NODES * sizeof(int);         // 26,229,376
    const size_t off_HS     = off_scan   + 4096;                                  // 26,233,472
    const size_t off_HR     = off_HS     + (size_t)N_NODES * 256;                 // +12.8 MB
    const size_t off_elat_s = off_HR     + (size_t)N_NODES * 256;                 // +12.8 MB
    const size_t need       = off_elat_s + (size_t)N_EDGES * 256;                 // ~256.6 MB
    if (ws_size < need) return;   // ws >= 436 MB confirmed empirically (r6 tier_s ran)

    float* aggr   = (float*)(ws + off_aggr);
    uint4* wpack  = (uint4*)(ws + off_wpack);
    int*   cnt    = (int*)(ws + off_cnt);
    int*   cursor = (int*)(ws + off_cursor);
    int*   bsum   = (int*)(ws + off_scan);
    int*   boff   = (int*)(ws + off_scan + 2048);
    u16*   HS     = (u16*)(ws + off_HS);
    u16*   HR     = (u16*)(ws + off_HR);
    u16*   elat_s = (u16*)(ws + off_elat_s);

    hipMemsetAsync(aggr, 0, (size_t)N_NODES * 128 * sizeof(float), stream);
    hipMemsetAsync(cnt, 0, (size_t)N_NODES * sizeof(int), stream);
    pack_weights<<<56, 256, 0, stream>>>(me_w1, me_w2, nf_w1, nf_w2, wpack);
    convert_node<<<3125, 256, 0, stream>>>(node, (uint4*)node_bf);
    hist_kernel<<<(N_EDGES + 255) / 256, 256, 0, stream>>>(receivers, cnt);
    scan1<<<SCAN_NB, 256, 0, stream>>>(cnt, bsum);
    scan2<<<1, 256, 0, stream>>>(bsum, boff);
    scan3<<<SCAN_NB, 256, 0, stream>>>(cnt, boff, cursor);
    scatter_kernel<<<(N_EDGES + 255) / 256, 256, 0, stream>>>(
        senders, receivers, cursor, sorted_eid, pos_of, snd_sorted, rcv_sorted);
    proj_nodes<<<(N_NODES + 63) / 64, 256, 0, stream>>>(node_bf, wpack, (uint4*)HS, (uint4*)HR);
    permute_elat<<<50000, 256, 0, stream>>>(elat, pos_of, (uint4*)elat_s);
    edge_sum<<<768, 256, 0, stream>>>(HS, HR, elat_s,
                                      snd_sorted, rcv_sorted, sorted_eid,
                                      me_b1, me_b2, me_g, me_be,
                                      wpack, wpack + 6144,
                                      out_edges, aggr);
    node_mlp_kernel<<<782, 256, 0, stream>>>(node, aggr,
                                             nf_b1, nf_b2, nf_g, nf_be,
                                             wpack + 8192, wpack + 12288,
                                             out_nodes);
}